// Round 16
// baseline (345.046 us; speedup 1.0000x reference)
//
#include <hip/hip_runtime.h>
#include <math.h>

#define N_NODES 50000
#define N_EDGES 800000
#define IN_CH 128
#define HID 256
#define OUT_CH 40

#define CAP 64          // 4 replicas x 16 slots per node (deg~Poisson(16), max ~35)
#define RSL 16          // slots per replica
#define OV_CAP 65536    // overflow safety net (correctness only)

typedef __attribute__((ext_vector_type(8))) short short8;
typedef __attribute__((ext_vector_type(4))) float floatx4;
typedef __attribute__((ext_vector_type(2))) float floatx2;

typedef __attribute__((address_space(3))) void lds_void;
typedef const __attribute__((address_space(1))) void glb_void;

__device__ __forceinline__ unsigned short f2bf(float f) {
    unsigned int u = __float_as_uint(f);
    u += 0x7fff + ((u >> 16) & 1);
    return (unsigned short)(u >> 16);
}
__device__ __forceinline__ float bf2f(unsigned short h) {
    return __uint_as_float(((unsigned int)h) << 16);
}

// ---- fp8 e4m3fn (OCP) encode/decode (unbiased RNE) ----
__device__ __forceinline__ unsigned char f2fp8(float f) {
    f = fminf(448.f, fmaxf(-448.f, f));
    unsigned u = __float_as_uint(f);
    unsigned s = (u >> 24) & 0x80u;
    u &= 0x7fffffffu;
    if (u < 0x3c800000u) return (unsigned char)s;   // flush |f| < 2^-6
    unsigned r = u + 0x7FFFFu + ((u >> 20) & 1u);   // unbiased RNE
    unsigned em = (r >> 20) - 960u;
    return (unsigned char)(s | em);
}

__device__ __forceinline__ void fp8x4_to_f32x4(unsigned int q, float* o) {
#if defined(__has_builtin) && __has_builtin(__builtin_amdgcn_cvt_pk_f32_fp8)
    floatx2 lo = __builtin_amdgcn_cvt_pk_f32_fp8((int)q, false);
    floatx2 hi = __builtin_amdgcn_cvt_pk_f32_fp8((int)q, true);
    o[0] = lo.x; o[1] = lo.y; o[2] = hi.x; o[3] = hi.y;
#else
#pragma unroll
    for (int i = 0; i < 4; ++i) {
        unsigned b = (q >> (8 * i)) & 0xffu;
        unsigned em = b & 0x7fu;
        unsigned bits = em ? (((b & 0x80u) << 24) | ((em << 20) + (120u << 23)))
                           : ((b & 0x80u) << 24);
        o[i] = __uint_as_float(bits);
    }
#endif
}

// ============== CSR build: single pass + 4-way REPLICATED counters (r13) ===
// Round-3/13 A/B showed ~50us floor survives an 8x fetch reduction -> floor is
// the 800K same-address atomic chains (deg<=~35 serialized ops per counter).
// Replica r = e&3 cuts the max chain ~4x. Slot layout [d*64 + r*16 + slot]
// keeps replica runs 16-aligned so the 16-lane gather groups map 1:1.
__global__ __launch_bounds__(256) void fill_fixed(const int* __restrict__ src,
                                                  const int* __restrict__ dst,
                                                  const float* __restrict__ ew,
                                                  int* __restrict__ cnt4,
                                                  int2* __restrict__ csr,
                                                  int4* __restrict__ ov,
                                                  int* __restrict__ ov_cnt) {
    int e = blockIdx.x * 256 + threadIdx.x;
    if (e >= N_EDGES) return;
    int d = dst[e];
    int r = e & 3;
    int slot = atomicAdd(&cnt4[d * 4 + r], 1);
    if (slot < RSL) {
        csr[(size_t)d * CAP + r * RSL + slot] = make_int2(src[e], __float_as_int(ew[e]));
    } else {
        int oi = atomicAdd(ov_cnt, 1);
        if (oi < OV_CAP)
            ov[oi] = make_int4(src[e], __float_as_int(ew[e]), d, 0);
    }
}

// ------------- all three weight casts fused: Wt[m][k] = bf16(W[k][m]) ------
__global__ __launch_bounds__(256) void wt_cast_all(const float* __restrict__ W1,
                                                   const float* __restrict__ W2,
                                                   const float* __restrict__ W3,
                                                   short* __restrict__ Wt1,
                                                   short* __restrict__ Wt2,
                                                   short* __restrict__ Wt3) {
    int idx = blockIdx.x * 256 + threadIdx.x;
    const int n1 = IN_CH * HID, n2 = HID * HID, n3 = HID * OUT_CH;
    if (idx < n1) {
        int m = idx / IN_CH, k = idx - m * IN_CH;
        Wt1[idx] = (short)f2bf(W1[(size_t)k * HID + m]);
    } else if (idx < n1 + n2) {
        int j = idx - n1;
        int m = j / HID, k = j - m * HID;
        Wt2[j] = (short)f2bf(W2[(size_t)k * HID + m]);
    } else if (idx < n1 + n2 + n3) {
        int j = idx - n1 - n2;
        int m = j / HID, k = j - m * HID;
        Wt3[j] = (short)f2bf(W3[(size_t)k * OUT_CH + m]);
    }
}

// ---- x cast to fp8, CHUNK-MAJOR layout: xq[chunk][node][64], chunk=feat/64
// slice size = 50000*64 B = 3.2 MB < 4 MiB per-XCD L2.
__global__ __launch_bounds__(256) void cast_x_fp8(const float4* __restrict__ x4,
                                                  unsigned char* __restrict__ xq,
                                                  int total4) {
    int i = blockIdx.x * 256 + threadIdx.x;
    if (i >= total4) return;
    float4 v = x4[i];
    uchar4 q = make_uchar4(f2fp8(v.x), f2fp8(v.y), f2fp8(v.z), f2fp8(v.w));
    int n = i >> 5;              // node (32 float4 per 128-wide row)
    int p = (i & 31) * 4;        // feature position 0..124
    int chunk = p >> 6;
    size_t off = (size_t)chunk * ((size_t)N_NODES * 64) + (size_t)n * 64 + (p & 63);
    *(uchar4*)(xq + off) = q;
}

// -------- gather layer1: agg(x fp8) -> bf16, feature-chunked ---------------
// 16 lanes/node x 4 feats; blockIdx.y = chunk. Replica-run outer loop (r13):
// each 16-slot run is a validity prefix for the 16-lane group -> inner loop
// unchanged from the verified r3 version.
__global__ __launch_bounds__(256) void gather_x_fp8(const unsigned char* __restrict__ xq,
                                                    const int* __restrict__ cnt4,
                                                    const int2* __restrict__ csr,
                                                    const int4* __restrict__ ov,
                                                    const int* __restrict__ ov_cnt,
                                                    unsigned short* __restrict__ out) {
    int node = blockIdx.x * 16 + (threadIdx.x >> 4);
    int g = threadIdx.x & 15;
    int chunk = blockIdx.y;
    if (node >= N_NODES) return;
    const unsigned char* tab = xq + (size_t)chunk * ((size_t)N_NODES * 64);
    int4 c4 = *(const int4*)(cnt4 + node * 4);
    int beg0 = node * CAP;
    float a[4] = {};
    auto run = [&](int c, int base) {
        if (c <= 0) return;
        int sv = 0; float wv = 0.f;
        if (g < c) {
            int2 iv = csr[base + g];
            sv = iv.x; wv = __int_as_float(iv.y);
        }
        int j = 0;
        for (; j + 4 <= c; j += 4) {
            int s0 = __shfl(sv, j, 16),     s1 = __shfl(sv, j + 1, 16);
            int s2 = __shfl(sv, j + 2, 16), s3 = __shfl(sv, j + 3, 16);
            float w0 = __shfl(wv, j, 16),     w1 = __shfl(wv, j + 1, 16);
            float w2 = __shfl(wv, j + 2, 16), w3 = __shfl(wv, j + 3, 16);
            unsigned q0 = *(const unsigned*)(tab + (size_t)s0 * 64 + g * 4);
            unsigned q1 = *(const unsigned*)(tab + (size_t)s1 * 64 + g * 4);
            unsigned q2 = *(const unsigned*)(tab + (size_t)s2 * 64 + g * 4);
            unsigned q3 = *(const unsigned*)(tab + (size_t)s3 * 64 + g * 4);
            float d0[4], d1[4], d2[4], d3[4];
            fp8x4_to_f32x4(q0, d0); fp8x4_to_f32x4(q1, d1);
            fp8x4_to_f32x4(q2, d2); fp8x4_to_f32x4(q3, d3);
#pragma unroll
            for (int t = 0; t < 4; ++t)
                a[t] += d0[t] * w0 + d1[t] * w1 + d2[t] * w2 + d3[t] * w3;
        }
        for (; j < c; ++j) {
            int s0 = __shfl(sv, j, 16);
            float w0 = __shfl(wv, j, 16);
            unsigned q0 = *(const unsigned*)(tab + (size_t)s0 * 64 + g * 4);
            float d0[4];
            fp8x4_to_f32x4(q0, d0);
#pragma unroll
            for (int t = 0; t < 4; ++t) a[t] += d0[t] * w0;
        }
    };
    run(min(c4.x, RSL), beg0);
    run(min(c4.y, RSL), beg0 + RSL);
    run(min(c4.z, RSL), beg0 + 2 * RSL);
    run(min(c4.w, RSL), beg0 + 3 * RSL);
    int L = min(*ov_cnt, OV_CAP);
    for (int i = 0; i < L; ++i) {
        int4 e = ov[i];
        if (e.z == node) {
            float w0 = __int_as_float(e.y);
            unsigned q0 = *(const unsigned*)(tab + (size_t)e.x * 64 + g * 4);
            float d0[4];
            fp8x4_to_f32x4(q0, d0);
#pragma unroll
            for (int t = 0; t < 4; ++t) a[t] += d0[t] * w0;
        }
    }
    ushort4 o = make_ushort4(f2bf(a[0]), f2bf(a[1]), f2bf(a[2]), f2bf(a[3]));
    *(ushort4*)(out + (size_t)node * 128 + chunk * 64 + g * 4) = o;
}

// ---- gather layer2: agg(h fp8 chunk-major) -> bias+relu -> bf16 -----------
// 16 lanes/node x 4 feats; blockIdx.y = chunk. Replica-run outer loop (r13).
__global__ __launch_bounds__(256) void gather_h_fp8(const unsigned char* __restrict__ h,
                                                    const int* __restrict__ cnt4,
                                                    const int2* __restrict__ csr,
                                                    const int4* __restrict__ ov,
                                                    const int* __restrict__ ov_cnt,
                                                    const float* __restrict__ bias,
                                                    unsigned short* __restrict__ out) {
    int node = blockIdx.x * 16 + (threadIdx.x >> 4);
    int g = threadIdx.x & 15;
    int chunk = blockIdx.y;
    if (node >= N_NODES) return;
    const unsigned char* tab = h + (size_t)chunk * ((size_t)N_NODES * 64);
    int4 c4 = *(const int4*)(cnt4 + node * 4);
    int beg0 = node * CAP;
    float acc[4] = {};
    auto run = [&](int c, int base) {
        if (c <= 0) return;
        int sv = 0; float wv = 0.f;
        if (g < c) {
            int2 iv = csr[base + g];
            sv = iv.x; wv = __int_as_float(iv.y);
        }
        int j = 0;
        for (; j + 4 <= c; j += 4) {
            int s0 = __shfl(sv, j, 16),     s1 = __shfl(sv, j + 1, 16);
            int s2 = __shfl(sv, j + 2, 16), s3 = __shfl(sv, j + 3, 16);
            float w0 = __shfl(wv, j, 16),     w1 = __shfl(wv, j + 1, 16);
            float w2 = __shfl(wv, j + 2, 16), w3 = __shfl(wv, j + 3, 16);
            unsigned q0 = *(const unsigned*)(tab + (size_t)s0 * 64 + g * 4);
            unsigned q1 = *(const unsigned*)(tab + (size_t)s1 * 64 + g * 4);
            unsigned q2 = *(const unsigned*)(tab + (size_t)s2 * 64 + g * 4);
            unsigned q3 = *(const unsigned*)(tab + (size_t)s3 * 64 + g * 4);
            float d0[4], d1[4], d2[4], d3[4];
            fp8x4_to_f32x4(q0, d0); fp8x4_to_f32x4(q1, d1);
            fp8x4_to_f32x4(q2, d2); fp8x4_to_f32x4(q3, d3);
#pragma unroll
            for (int t = 0; t < 4; ++t)
                acc[t] += d0[t] * w0 + d1[t] * w1 + d2[t] * w2 + d3[t] * w3;
        }
        for (; j < c; ++j) {
            int s0 = __shfl(sv, j, 16);
            float w0 = __shfl(wv, j, 16);
            unsigned q0 = *(const unsigned*)(tab + (size_t)s0 * 64 + g * 4);
            float d0[4];
            fp8x4_to_f32x4(q0, d0);
#pragma unroll
            for (int t = 0; t < 4; ++t) acc[t] += d0[t] * w0;
        }
    };
    run(min(c4.x, RSL), beg0);
    run(min(c4.y, RSL), beg0 + RSL);
    run(min(c4.z, RSL), beg0 + 2 * RSL);
    run(min(c4.w, RSL), beg0 + 3 * RSL);
    int L = min(*ov_cnt, OV_CAP);
    for (int i = 0; i < L; ++i) {
        int4 e = ov[i];
        if (e.z == node) {
            float w0 = __int_as_float(e.y);
            unsigned q0 = *(const unsigned*)(tab + (size_t)e.x * 64 + g * 4);
            float d0[4];
            fp8x4_to_f32x4(q0, d0);
#pragma unroll
            for (int t = 0; t < 4; ++t) acc[t] += d0[t] * w0;
        }
    }
    ushort4 o;
    {
        float r0 = fmaxf(acc[0] + bias[chunk * 64 + g * 4 + 0], 0.f);
        float r1 = fmaxf(acc[1] + bias[chunk * 64 + g * 4 + 1], 0.f);
        float r2 = fmaxf(acc[2] + bias[chunk * 64 + g * 4 + 2], 0.f);
        float r3 = fmaxf(acc[3] + bias[chunk * 64 + g * 4 + 3], 0.f);
        o = make_ushort4(f2bf(r0), f2bf(r1), f2bf(r2), f2bf(r3));
    }
    *(ushort4*)(out + (size_t)node * 256 + chunk * 64 + g * 4) = o;
}

// --------------- bf16 MFMA GEMM: C[N,M] = A[N,K] @ Wt[M,K]^T ---------------
// BM=128, BN=64, BK=32; 4 waves (2x2). Staging via global_load_lds width=16:
// the XOR bank-swizzle is applied on the GLOBAL address (per-lane vaddr is
// free-form); LDS dest stays linear base+lane*16 as HW requires. OOB rows/cols
// clamp to a valid row — garbage flows only into never-stored C cells.
// OUT_MODE: 0=f32 row-major, 1=bf16 row-major, 2=fp8 row-major,
//           3=fp8 CHUNK-MAJOR ([col/64][row][64]) for L2-resident gathers.
template <int OUT_MODE>
__global__ __launch_bounds__(256) void mfma_gemm(const short* __restrict__ A,
                                                 const short* __restrict__ Wt,
                                                 void* __restrict__ Cout,
                                                 int N, int K, int M,
                                                 const float* __restrict__ bias,
                                                 int act) {
    __shared__ short As[128 * 32];
    __shared__ short Bs[64 * 32];
    const int tid = threadIdx.x;
    const int lane = tid & 63;
    const int wave = tid >> 6;
    const int wr = wave >> 1, wc = wave & 1;
    const int row0 = blockIdx.y * 128;
    const int col0 = blockIdx.x * 64;

    floatx4 acc[4][2];
#pragma unroll
    for (int t = 0; t < 4; ++t)
#pragma unroll
        for (int u = 0; u < 2; ++u) acc[t][u] = (floatx4){0.f, 0.f, 0.f, 0.f};

    for (int k0 = 0; k0 < K; k0 += 32) {
        // A tile: 512 chunks of 16B; wave w covers [w*128, w*128+128), 2 insts
#pragma unroll
        for (int j = 0; j < 2; ++j) {
            int c = wave * 128 + j * 64 + lane;
            int r = c >> 2, cc = c & 3;
            int gr = min(row0 + r, N - 1);
            const short* gp = A + (size_t)gr * K + k0 + ((cc ^ ((r >> 1) & 3)) << 3);
            __builtin_amdgcn_global_load_lds(
                (glb_void*)gp,
                (lds_void*)(As + (size_t)(wave * 128 + j * 64) * 8), 16, 0, 0);
        }
        // B tile: 256 chunks; wave w covers [w*64, w*64+64), 1 inst
        {
            int c = wave * 64 + lane;
            int r = c >> 2, cc = c & 3;
            int gn = min(col0 + r, M - 1);
            const short* gp = Wt + (size_t)gn * K + k0 + ((cc ^ ((r >> 1) & 3)) << 3);
            __builtin_amdgcn_global_load_lds(
                (glb_void*)gp,
                (lds_void*)(Bs + (size_t)(wave * 64) * 8), 16, 0, 0);
        }
        __syncthreads();

        short8 bf[2];
#pragma unroll
        for (int u = 0; u < 2; ++u) {
            int n = wc * 32 + u * 16 + (lane & 15);
            int ch = (lane >> 4) ^ ((n >> 1) & 3);
            bf[u] = *(const short8*)&Bs[n * 32 + (ch << 3)];
        }
#pragma unroll
        for (int t = 0; t < 4; ++t) {
            int r = wr * 64 + t * 16 + (lane & 15);
            int ch = (lane >> 4) ^ ((r >> 1) & 3);
            short8 af = *(const short8*)&As[r * 32 + (ch << 3)];
            acc[t][0] = __builtin_amdgcn_mfma_f32_16x16x32_bf16(af, bf[0], acc[t][0], 0, 0, 0);
            acc[t][1] = __builtin_amdgcn_mfma_f32_16x16x32_bf16(af, bf[1], acc[t][1], 0, 0, 0);
        }
        __syncthreads();
    }

#pragma unroll
    for (int t = 0; t < 4; ++t) {
#pragma unroll
        for (int u = 0; u < 2; ++u) {
            int gcol = col0 + wc * 32 + u * 16 + (lane & 15);
            if (gcol >= M) continue;
            float bv = bias ? bias[gcol] : 0.f;
#pragma unroll
            for (int reg = 0; reg < 4; ++reg) {
                int grow = row0 + wr * 64 + t * 16 + (lane >> 4) * 4 + reg;
                if (grow >= N) continue;
                float v = acc[t][u][reg] + bv;
                if (act) v = fmaxf(v, 0.f);
                if (OUT_MODE == 1)
                    ((unsigned short*)Cout)[(size_t)grow * M + gcol] = f2bf(v);
                else if (OUT_MODE == 2)
                    ((unsigned char*)Cout)[(size_t)grow * M + gcol] = f2fp8(v);
                else if (OUT_MODE == 3)
                    ((unsigned char*)Cout)[(size_t)(gcol >> 6) * ((size_t)N * 64) +
                                           (size_t)grow * 64 + (gcol & 63)] = f2fp8(v);
                else
                    ((float*)Cout)[(size_t)grow * M + gcol] = v;
            }
        }
    }
}

// ---- final: gather bf16 40-wide rows + bias + log_softmax, wave/node ------
// Replica-run aware (r13): lane valid iff (lane&15) < cnt of its 16-run;
// shuffle source lanes walk each run's prefix.
__global__ __launch_bounds__(256) void gather_lsm(const unsigned short* __restrict__ h,
                                                  const int* __restrict__ cnt4,
                                                  const int2* __restrict__ csr,
                                                  const int4* __restrict__ ov,
                                                  const int* __restrict__ ov_cnt,
                                                  const float* __restrict__ b,
                                                  float* __restrict__ out, int n) {
    int wave = threadIdx.x >> 6;
    int lane = threadIdx.x & 63;
    int node = blockIdx.x * 4 + wave;
    if (node >= n) return;
    int4 c4 = *(const int4*)(cnt4 + node * 4);
    int c0 = min(c4.x, RSL), c1 = min(c4.y, RSL);
    int c2 = min(c4.z, RSL), c3 = min(c4.w, RSL);
    int beg = node * CAP;
    int cmine = (lane < 16) ? c0 : (lane < 32) ? c1 : (lane < 48) ? c2 : c3;
    int sv = 0; float wv = 0.f;
    if ((lane & 15) < cmine) {
        int2 iv = csr[beg + lane];
        sv = iv.x; wv = __int_as_float(iv.y);
    }
    float acc = 0.f;
    auto run = [&](int c, int b0) {
        int j = 0;
        for (; j + 4 <= c; j += 4) {
            int s0 = __shfl(sv, b0 + j, 64),     s1 = __shfl(sv, b0 + j + 1, 64);
            int s2 = __shfl(sv, b0 + j + 2, 64), s3 = __shfl(sv, b0 + j + 3, 64);
            float w0 = __shfl(wv, b0 + j, 64),     w1 = __shfl(wv, b0 + j + 1, 64);
            float w2 = __shfl(wv, b0 + j + 2, 64), w3 = __shfl(wv, b0 + j + 3, 64);
            float v0 = 0.f, v1 = 0.f, v2 = 0.f, v3 = 0.f;
            if (lane < OUT_CH) {
                v0 = bf2f(h[(size_t)s0 * OUT_CH + lane]);
                v1 = bf2f(h[(size_t)s1 * OUT_CH + lane]);
                v2 = bf2f(h[(size_t)s2 * OUT_CH + lane]);
                v3 = bf2f(h[(size_t)s3 * OUT_CH + lane]);
            }
            acc += v0 * w0 + v1 * w1 + v2 * w2 + v3 * w3;
        }
        for (; j < c; ++j) {
            int s0 = __shfl(sv, b0 + j, 64);
            float w0 = __shfl(wv, b0 + j, 64);
            if (lane < OUT_CH) acc += bf2f(h[(size_t)s0 * OUT_CH + lane]) * w0;
        }
    };
    run(c0, 0);
    run(c1, 16);
    run(c2, 32);
    run(c3, 48);
    int L = min(*ov_cnt, OV_CAP);
    for (int i = 0; i < L; ++i) {
        int4 e = ov[i];
        if (e.z == node && lane < OUT_CH)
            acc += bf2f(h[(size_t)e.x * OUT_CH + lane]) * __int_as_float(e.y);
    }
    float val = 0.f, v = -INFINITY;
    if (lane < OUT_CH) {
        val = acc + b[lane];
        v = val;
    }
#pragma unroll
    for (int off = 32; off; off >>= 1)
        v = fmaxf(v, __shfl_xor(v, off, 64));
    float ex = (lane < OUT_CH) ? expf(val - v) : 0.f;
#pragma unroll
    for (int off = 32; off; off >>= 1)
        ex += __shfl_xor(ex, off, 64);
    float ls = logf(ex);
    if (lane < OUT_CH) out[(size_t)node * OUT_CH + lane] = val - v - ls;
}

// ---------------------------------------------------------------------------
extern "C" void kernel_launch(void* const* d_in, const int* in_sizes, int n_in,
                              void* d_out, int out_size, void* d_ws, size_t ws_size,
                              hipStream_t stream) {
    const float* x   = (const float*)d_in[0];
    const int*  eidx = (const int*)d_in[1];
    const float* ew  = (const float*)d_in[2];
    const float* W1  = (const float*)d_in[3];
    const float* b1  = (const float*)d_in[4];
    const float* W2  = (const float*)d_in[5];
    const float* b2  = (const float*)d_in[6];
    const float* W3  = (const float*)d_in[7];
    const float* b3  = (const float*)d_in[8];
    const int* src = eidx;
    const int* dst = eidx + N_EDGES;
    float* out = (float*)d_out;

    short* region0 = (short*)d_ws;                          // xq(fp8) / h2p(fp8)
    short* region1 = region0 + (size_t)N_NODES * HID;       // aggX / h3p
    short* H1   = region1 + (size_t)N_NODES * IN_CH;
    short* H2   = H1 + (size_t)N_NODES * HID;
    short* Wt1  = H2 + (size_t)N_NODES * HID;
    short* Wt2  = Wt1 + HID * IN_CH;
    short* Wt3  = Wt2 + HID * HID;
    int*   cnt     = (int*)(Wt3 + OUT_CH * HID);            // 4*N_NODES replica counters
    int*   ov_cnt  = cnt + 4 * N_NODES;
    int2*  csr     = (int2*)(cnt + 4 * N_NODES + 4);        // N_NODES*CAP int2 (16B-aligned)
    int4*  ovbuf   = (int4*)(csr + (size_t)N_NODES * CAP);  // OV_CAP int4

    unsigned char* xq  = (unsigned char*)region0;           // fp8 chunk-major, 6.4 MB
    unsigned char* h2p = (unsigned char*)region0;           // fp8 chunk-major, 12.8 MB
    short* aggX = region1;
    short* h3p  = region1;

    dim3 blk(256);

    // ---- CSR build: one memset + one single-pass edge scan (replicated cnt)
    hipMemsetAsync(cnt, 0, (4 * N_NODES + 1) * sizeof(int), stream);
    fill_fixed<<<(N_EDGES + 255) / 256, blk, 0, stream>>>(src, dst, ew, cnt, csr, ovbuf, ov_cnt);

    // ---- weight + x casts
    {
        int tot = IN_CH * HID + HID * HID + HID * OUT_CH;
        wt_cast_all<<<(tot + 255) / 256, blk, 0, stream>>>(W1, W2, W3, Wt1, Wt2, Wt3);
    }
    cast_x_fp8<<<(N_NODES * IN_CH / 4 + 255) / 256, blk, 0, stream>>>(
        (const float4*)x, xq, N_NODES * IN_CH / 4);

    // ---- layer 1 (swapped): aggX = gather(xq); H1 = relu(aggX@W1 + b1)
    {
        dim3 grid((N_NODES + 15) / 16, 2);   // y = feature chunk (2 x 64)
        gather_x_fp8<<<grid, blk, 0, stream>>>(
            xq, cnt, csr, ovbuf, ov_cnt, (unsigned short*)aggX);
    }
    {
        dim3 grid((HID + 63) / 64, (N_NODES + 127) / 128);
        mfma_gemm<1><<<grid, blk, 0, stream>>>(aggX, Wt1, H1, N_NODES, IN_CH, HID, b1, 1);
    }

    // ---- layer 2: h2p = fp8(H1@W2) chunk-major ; H2 = relu(gather(h2p) + b2)
    {
        dim3 grid((HID + 63) / 64, (N_NODES + 127) / 128);
        mfma_gemm<3><<<grid, blk, 0, stream>>>(H1, Wt2, h2p, N_NODES, HID, HID, nullptr, 0);
    }
    {
        dim3 grid((N_NODES + 15) / 16, 4);   // y = feature chunk (4 x 64)
        gather_h_fp8<<<grid, blk, 0, stream>>>(
            h2p, cnt, csr, ovbuf, ov_cnt, b2, (unsigned short*)H2);
    }

    // ---- layer 3: h3p = H2@W3 (bf16) ; out = log_softmax(gather(h3p) + b3)
    {
        dim3 grid((OUT_CH + 63) / 64, (N_NODES + 127) / 128);
        mfma_gemm<1><<<grid, blk, 0, stream>>>(H2, Wt3, h3p, N_NODES, HID, OUT_CH, nullptr, 0);
    }
    gather_lsm<<<(N_NODES + 3) / 4, blk, 0, stream>>>(
        (const unsigned short*)h3p, cnt, csr, ovbuf, ov_cnt, b3, out, N_NODES);
}

// Round 17
// 313.698 us; speedup vs baseline: 1.0999x; 1.0999x over previous
//
#include <hip/hip_runtime.h>
#include <math.h>

#define N_NODES 50000
#define N_EDGES 800000
#define IN_CH 128
#define HID 256
#define OUT_CH 40

#define CAP 64          // 4 replicas x 16 slots per node (deg~Poisson(16), max ~35)
#define RSL 16          // slots per replica
#define OV_CAP 65536    // overflow safety net (correctness only)

typedef __attribute__((ext_vector_type(8))) short short8;
typedef __attribute__((ext_vector_type(4))) float floatx4;
typedef __attribute__((ext_vector_type(2))) float floatx2;

typedef __attribute__((address_space(3))) void lds_void;
typedef const __attribute__((address_space(1))) void glb_void;

__device__ __forceinline__ unsigned short f2bf(float f) {
    unsigned int u = __float_as_uint(f);
    u += 0x7fff + ((u >> 16) & 1);
    return (unsigned short)(u >> 16);
}
__device__ __forceinline__ float bf2f(unsigned short h) {
    return __uint_as_float(((unsigned int)h) << 16);
}

// ---- fp8 e4m3fn (OCP) encode/decode (unbiased RNE) ----
__device__ __forceinline__ unsigned char f2fp8(float f) {
    f = fminf(448.f, fmaxf(-448.f, f));
    unsigned u = __float_as_uint(f);
    unsigned s = (u >> 24) & 0x80u;
    u &= 0x7fffffffu;
    if (u < 0x3c800000u) return (unsigned char)s;   // flush |f| < 2^-6
    unsigned r = u + 0x7FFFFu + ((u >> 20) & 1u);   // unbiased RNE
    unsigned em = (r >> 20) - 960u;
    return (unsigned char)(s | em);
}

__device__ __forceinline__ void fp8x4_to_f32x4(unsigned int q, float* o) {
#if defined(__has_builtin) && __has_builtin(__builtin_amdgcn_cvt_pk_f32_fp8)
    floatx2 lo = __builtin_amdgcn_cvt_pk_f32_fp8((int)q, false);
    floatx2 hi = __builtin_amdgcn_cvt_pk_f32_fp8((int)q, true);
    o[0] = lo.x; o[1] = lo.y; o[2] = hi.x; o[3] = hi.y;
#else
#pragma unroll
    for (int i = 0; i < 4; ++i) {
        unsigned b = (q >> (8 * i)) & 0xffu;
        unsigned em = b & 0x7fu;
        unsigned bits = em ? (((b & 0x80u) << 24) | ((em << 20) + (120u << 23)))
                           : ((b & 0x80u) << 24);
        o[i] = __uint_as_float(bits);
    }
#endif
}

// ============== CSR build: single pass + 4-way REPLICATED counters (r13) ===
// Round-3/13 A/B: ~50us floor survives an 8x fetch cut -> floor = same-address
// atomic chains. Replica r = e&3 cuts the max chain ~4x.
__global__ __launch_bounds__(256) void fill_fixed(const int* __restrict__ src,
                                                  const int* __restrict__ dst,
                                                  const float* __restrict__ ew,
                                                  int* __restrict__ cnt4,
                                                  int2* __restrict__ csr,
                                                  int4* __restrict__ ov,
                                                  int* __restrict__ ov_cnt) {
    int e = blockIdx.x * 256 + threadIdx.x;
    if (e >= N_EDGES) return;
    int d = dst[e];
    int r = e & 3;
    int slot = atomicAdd(&cnt4[d * 4 + r], 1);
    if (slot < RSL) {
        csr[(size_t)d * CAP + r * RSL + slot] = make_int2(src[e], __float_as_int(ew[e]));
    } else {
        int oi = atomicAdd(ov_cnt, 1);
        if (oi < OV_CAP)
            ov[oi] = make_int4(src[e], __float_as_int(ew[e]), d, 0);
    }
}

// ============== compact replica runs -> contiguous prefix + total (r16) ====
// Round-16 profile: replica-run gathers read all 64 slots/node (4x csr
// traffic, FETCH 125 MB on gather_h). Compact once (read-all-then-write-all,
// in-place safe: each node owned by one 16-lane group) so gathers read only
// the occupied prefix. ~13 MB traffic total.
__global__ __launch_bounds__(256) void compact_csr(const int* __restrict__ cnt4,
                                                   int2* __restrict__ csr,
                                                   int* __restrict__ cnt) {
    int node = blockIdx.x * 16 + (threadIdx.x >> 4);
    int g = threadIdx.x & 15;
    if (node >= N_NODES) return;
    int4 c4 = *(const int4*)(cnt4 + node * 4);
    int c0 = min(c4.x, RSL), c1 = min(c4.y, RSL);
    int c2 = min(c4.z, RSL), c3 = min(c4.w, RSL);
    size_t base = (size_t)node * CAP;
    int2 s1, s2, s3;
    bool v1 = g < c1, v2 = g < c2, v3 = g < c3;
    if (v1) s1 = csr[base + RSL + g];
    if (v2) s2 = csr[base + 2 * RSL + g];
    if (v3) s3 = csr[base + 3 * RSL + g];
    // replica 0 already at prefix [0,c0); write 1..3 after (reads done above)
    if (v1) csr[base + c0 + g] = s1;
    if (v2) csr[base + c0 + c1 + g] = s2;
    if (v3) csr[base + c0 + c1 + c2 + g] = s3;
    if (g == 0) cnt[node] = c0 + c1 + c2 + c3;
}

// ------------- all three weight casts fused: Wt[m][k] = bf16(W[k][m]) ------
__global__ __launch_bounds__(256) void wt_cast_all(const float* __restrict__ W1,
                                                   const float* __restrict__ W2,
                                                   const float* __restrict__ W3,
                                                   short* __restrict__ Wt1,
                                                   short* __restrict__ Wt2,
                                                   short* __restrict__ Wt3) {
    int idx = blockIdx.x * 256 + threadIdx.x;
    const int n1 = IN_CH * HID, n2 = HID * HID, n3 = HID * OUT_CH;
    if (idx < n1) {
        int m = idx / IN_CH, k = idx - m * IN_CH;
        Wt1[idx] = (short)f2bf(W1[(size_t)k * HID + m]);
    } else if (idx < n1 + n2) {
        int j = idx - n1;
        int m = j / HID, k = j - m * HID;
        Wt2[j] = (short)f2bf(W2[(size_t)k * HID + m]);
    } else if (idx < n1 + n2 + n3) {
        int j = idx - n1 - n2;
        int m = j / HID, k = j - m * HID;
        Wt3[j] = (short)f2bf(W3[(size_t)k * OUT_CH + m]);
    }
}

// ---- x cast to fp8, CHUNK-MAJOR layout: xq[chunk][node][64], chunk=feat/64
__global__ __launch_bounds__(256) void cast_x_fp8(const float4* __restrict__ x4,
                                                  unsigned char* __restrict__ xq,
                                                  int total4) {
    int i = blockIdx.x * 256 + threadIdx.x;
    if (i >= total4) return;
    float4 v = x4[i];
    uchar4 q = make_uchar4(f2fp8(v.x), f2fp8(v.y), f2fp8(v.z), f2fp8(v.w));
    int n = i >> 5;              // node (32 float4 per 128-wide row)
    int p = (i & 31) * 4;        // feature position 0..124
    int chunk = p >> 6;
    size_t off = (size_t)chunk * ((size_t)N_NODES * 64) + (size_t)n * 64 + (p & 63);
    *(uchar4*)(xq + off) = q;
}

// -------- gather layer1: agg(x fp8) -> bf16, feature-chunked (r3 form) -----
// 16 lanes/node x 4 feats; blockIdx.y = chunk; contiguous prefix after compact.
__global__ __launch_bounds__(256) void gather_x_fp8(const unsigned char* __restrict__ xq,
                                                    const int* __restrict__ cnt,
                                                    const int2* __restrict__ csr,
                                                    const int4* __restrict__ ov,
                                                    const int* __restrict__ ov_cnt,
                                                    unsigned short* __restrict__ out) {
    int node = blockIdx.x * 16 + (threadIdx.x >> 4);
    int g = threadIdx.x & 15;
    int chunk = blockIdx.y;
    if (node >= N_NODES) return;
    const unsigned char* tab = xq + (size_t)chunk * ((size_t)N_NODES * 64);
    int beg = node * CAP;
    int end = beg + min(cnt[node], CAP);
    float a[4] = {};
    for (int base = beg; base < end; base += 16) {
        int c = min(16, end - base);
        int sv = 0; float wv = 0.f;
        if (g < c) {
            int2 iv = csr[base + g];
            sv = iv.x; wv = __int_as_float(iv.y);
        }
        int j = 0;
        for (; j + 4 <= c; j += 4) {
            int s0 = __shfl(sv, j, 16),     s1 = __shfl(sv, j + 1, 16);
            int s2 = __shfl(sv, j + 2, 16), s3 = __shfl(sv, j + 3, 16);
            float w0 = __shfl(wv, j, 16),     w1 = __shfl(wv, j + 1, 16);
            float w2 = __shfl(wv, j + 2, 16), w3 = __shfl(wv, j + 3, 16);
            unsigned q0 = *(const unsigned*)(tab + (size_t)s0 * 64 + g * 4);
            unsigned q1 = *(const unsigned*)(tab + (size_t)s1 * 64 + g * 4);
            unsigned q2 = *(const unsigned*)(tab + (size_t)s2 * 64 + g * 4);
            unsigned q3 = *(const unsigned*)(tab + (size_t)s3 * 64 + g * 4);
            float d0[4], d1[4], d2[4], d3[4];
            fp8x4_to_f32x4(q0, d0); fp8x4_to_f32x4(q1, d1);
            fp8x4_to_f32x4(q2, d2); fp8x4_to_f32x4(q3, d3);
#pragma unroll
            for (int t = 0; t < 4; ++t)
                a[t] += d0[t] * w0 + d1[t] * w1 + d2[t] * w2 + d3[t] * w3;
        }
        for (; j < c; ++j) {
            int s0 = __shfl(sv, j, 16);
            float w0 = __shfl(wv, j, 16);
            unsigned q0 = *(const unsigned*)(tab + (size_t)s0 * 64 + g * 4);
            float d0[4];
            fp8x4_to_f32x4(q0, d0);
#pragma unroll
            for (int t = 0; t < 4; ++t) a[t] += d0[t] * w0;
        }
    }
    int L = min(*ov_cnt, OV_CAP);
    for (int i = 0; i < L; ++i) {
        int4 e = ov[i];
        if (e.z == node) {
            float w0 = __int_as_float(e.y);
            unsigned q0 = *(const unsigned*)(tab + (size_t)e.x * 64 + g * 4);
            float d0[4];
            fp8x4_to_f32x4(q0, d0);
#pragma unroll
            for (int t = 0; t < 4; ++t) a[t] += d0[t] * w0;
        }
    }
    ushort4 o = make_ushort4(f2bf(a[0]), f2bf(a[1]), f2bf(a[2]), f2bf(a[3]));
    *(ushort4*)(out + (size_t)node * 128 + chunk * 64 + g * 4) = o;
}

// ---- gather layer2: agg(h fp8 chunk-major) -> bias+relu -> bf16 (r3 form) -
__global__ __launch_bounds__(256) void gather_h_fp8(const unsigned char* __restrict__ h,
                                                    const int* __restrict__ cnt,
                                                    const int2* __restrict__ csr,
                                                    const int4* __restrict__ ov,
                                                    const int* __restrict__ ov_cnt,
                                                    const float* __restrict__ bias,
                                                    unsigned short* __restrict__ out) {
    int node = blockIdx.x * 16 + (threadIdx.x >> 4);
    int g = threadIdx.x & 15;
    int chunk = blockIdx.y;
    if (node >= N_NODES) return;
    const unsigned char* tab = h + (size_t)chunk * ((size_t)N_NODES * 64);
    int beg = node * CAP;
    int end = beg + min(cnt[node], CAP);
    float acc[4] = {};
    for (int base = beg; base < end; base += 16) {
        int c = min(16, end - base);
        int sv = 0; float wv = 0.f;
        if (g < c) {
            int2 iv = csr[base + g];
            sv = iv.x; wv = __int_as_float(iv.y);
        }
        int j = 0;
        for (; j + 4 <= c; j += 4) {
            int s0 = __shfl(sv, j, 16),     s1 = __shfl(sv, j + 1, 16);
            int s2 = __shfl(sv, j + 2, 16), s3 = __shfl(sv, j + 3, 16);
            float w0 = __shfl(wv, j, 16),     w1 = __shfl(wv, j + 1, 16);
            float w2 = __shfl(wv, j + 2, 16), w3 = __shfl(wv, j + 3, 16);
            unsigned q0 = *(const unsigned*)(tab + (size_t)s0 * 64 + g * 4);
            unsigned q1 = *(const unsigned*)(tab + (size_t)s1 * 64 + g * 4);
            unsigned q2 = *(const unsigned*)(tab + (size_t)s2 * 64 + g * 4);
            unsigned q3 = *(const unsigned*)(tab + (size_t)s3 * 64 + g * 4);
            float d0[4], d1[4], d2[4], d3[4];
            fp8x4_to_f32x4(q0, d0); fp8x4_to_f32x4(q1, d1);
            fp8x4_to_f32x4(q2, d2); fp8x4_to_f32x4(q3, d3);
#pragma unroll
            for (int t = 0; t < 4; ++t)
                acc[t] += d0[t] * w0 + d1[t] * w1 + d2[t] * w2 + d3[t] * w3;
        }
        for (; j < c; ++j) {
            int s0 = __shfl(sv, j, 16);
            float w0 = __shfl(wv, j, 16);
            unsigned q0 = *(const unsigned*)(tab + (size_t)s0 * 64 + g * 4);
            float d0[4];
            fp8x4_to_f32x4(q0, d0);
#pragma unroll
            for (int t = 0; t < 4; ++t) acc[t] += d0[t] * w0;
        }
    }
    int L = min(*ov_cnt, OV_CAP);
    for (int i = 0; i < L; ++i) {
        int4 e = ov[i];
        if (e.z == node) {
            float w0 = __int_as_float(e.y);
            unsigned q0 = *(const unsigned*)(tab + (size_t)e.x * 64 + g * 4);
            float d0[4];
            fp8x4_to_f32x4(q0, d0);
#pragma unroll
            for (int t = 0; t < 4; ++t) acc[t] += d0[t] * w0;
        }
    }
    ushort4 o;
    {
        float r0 = fmaxf(acc[0] + bias[chunk * 64 + g * 4 + 0], 0.f);
        float r1 = fmaxf(acc[1] + bias[chunk * 64 + g * 4 + 1], 0.f);
        float r2 = fmaxf(acc[2] + bias[chunk * 64 + g * 4 + 2], 0.f);
        float r3 = fmaxf(acc[3] + bias[chunk * 64 + g * 4 + 3], 0.f);
        o = make_ushort4(f2bf(r0), f2bf(r1), f2bf(r2), f2bf(r3));
    }
    *(ushort4*)(out + (size_t)node * 256 + chunk * 64 + g * 4) = o;
}

// --------------- bf16 MFMA GEMM: C[N,M] = A[N,K] @ Wt[M,K]^T ---------------
// BM=128, BN=64, BK=32; 4 waves (2x2). Staging via global_load_lds width=16.
// OUT_MODE: 0=f32, 1=bf16, 2=fp8 row-major, 3=fp8 CHUNK-MAJOR.
template <int OUT_MODE>
__global__ __launch_bounds__(256) void mfma_gemm(const short* __restrict__ A,
                                                 const short* __restrict__ Wt,
                                                 void* __restrict__ Cout,
                                                 int N, int K, int M,
                                                 const float* __restrict__ bias,
                                                 int act) {
    __shared__ short As[128 * 32];
    __shared__ short Bs[64 * 32];
    const int tid = threadIdx.x;
    const int lane = tid & 63;
    const int wave = tid >> 6;
    const int wr = wave >> 1, wc = wave & 1;
    const int row0 = blockIdx.y * 128;
    const int col0 = blockIdx.x * 64;

    floatx4 acc[4][2];
#pragma unroll
    for (int t = 0; t < 4; ++t)
#pragma unroll
        for (int u = 0; u < 2; ++u) acc[t][u] = (floatx4){0.f, 0.f, 0.f, 0.f};

    for (int k0 = 0; k0 < K; k0 += 32) {
#pragma unroll
        for (int j = 0; j < 2; ++j) {
            int c = wave * 128 + j * 64 + lane;
            int r = c >> 2, cc = c & 3;
            int gr = min(row0 + r, N - 1);
            const short* gp = A + (size_t)gr * K + k0 + ((cc ^ ((r >> 1) & 3)) << 3);
            __builtin_amdgcn_global_load_lds(
                (glb_void*)gp,
                (lds_void*)(As + (size_t)(wave * 128 + j * 64) * 8), 16, 0, 0);
        }
        {
            int c = wave * 64 + lane;
            int r = c >> 2, cc = c & 3;
            int gn = min(col0 + r, M - 1);
            const short* gp = Wt + (size_t)gn * K + k0 + ((cc ^ ((r >> 1) & 3)) << 3);
            __builtin_amdgcn_global_load_lds(
                (glb_void*)gp,
                (lds_void*)(Bs + (size_t)(wave * 64) * 8), 16, 0, 0);
        }
        __syncthreads();

        short8 bf[2];
#pragma unroll
        for (int u = 0; u < 2; ++u) {
            int n = wc * 32 + u * 16 + (lane & 15);
            int ch = (lane >> 4) ^ ((n >> 1) & 3);
            bf[u] = *(const short8*)&Bs[n * 32 + (ch << 3)];
        }
#pragma unroll
        for (int t = 0; t < 4; ++t) {
            int r = wr * 64 + t * 16 + (lane & 15);
            int ch = (lane >> 4) ^ ((r >> 1) & 3);
            short8 af = *(const short8*)&As[r * 32 + (ch << 3)];
            acc[t][0] = __builtin_amdgcn_mfma_f32_16x16x32_bf16(af, bf[0], acc[t][0], 0, 0, 0);
            acc[t][1] = __builtin_amdgcn_mfma_f32_16x16x32_bf16(af, bf[1], acc[t][1], 0, 0, 0);
        }
        __syncthreads();
    }

#pragma unroll
    for (int t = 0; t < 4; ++t) {
#pragma unroll
        for (int u = 0; u < 2; ++u) {
            int gcol = col0 + wc * 32 + u * 16 + (lane & 15);
            if (gcol >= M) continue;
            float bv = bias ? bias[gcol] : 0.f;
#pragma unroll
            for (int reg = 0; reg < 4; ++reg) {
                int grow = row0 + wr * 64 + t * 16 + (lane >> 4) * 4 + reg;
                if (grow >= N) continue;
                float v = acc[t][u][reg] + bv;
                if (act) v = fmaxf(v, 0.f);
                if (OUT_MODE == 1)
                    ((unsigned short*)Cout)[(size_t)grow * M + gcol] = f2bf(v);
                else if (OUT_MODE == 2)
                    ((unsigned char*)Cout)[(size_t)grow * M + gcol] = f2fp8(v);
                else if (OUT_MODE == 3)
                    ((unsigned char*)Cout)[(size_t)(gcol >> 6) * ((size_t)N * 64) +
                                           (size_t)grow * 64 + (gcol & 63)] = f2fp8(v);
                else
                    ((float*)Cout)[(size_t)grow * M + gcol] = v;
            }
        }
    }
}

// ---- final: gather bf16 40-wide rows + bias + log_softmax (r3 form) -------
__global__ __launch_bounds__(256) void gather_lsm(const unsigned short* __restrict__ h,
                                                  const int* __restrict__ cnt,
                                                  const int2* __restrict__ csr,
                                                  const int4* __restrict__ ov,
                                                  const int* __restrict__ ov_cnt,
                                                  const float* __restrict__ b,
                                                  float* __restrict__ out, int n) {
    int wave = threadIdx.x >> 6;
    int lane = threadIdx.x & 63;
    int node = blockIdx.x * 4 + wave;
    if (node >= n) return;
    int beg = node * CAP;
    int end = beg + min(cnt[node], CAP);
    float acc = 0.f;
    for (int base = beg; base < end; base += 64) {
        int c = min(64, end - base);
        int sv = 0; float wv = 0.f;
        if (lane < c) {
            int2 iv = csr[base + lane];
            sv = iv.x; wv = __int_as_float(iv.y);
        }
        int j = 0;
        for (; j + 4 <= c; j += 4) {
            int s0 = __shfl(sv, j, 64),     s1 = __shfl(sv, j + 1, 64);
            int s2 = __shfl(sv, j + 2, 64), s3 = __shfl(sv, j + 3, 64);
            float w0 = __shfl(wv, j, 64),     w1 = __shfl(wv, j + 1, 64);
            float w2 = __shfl(wv, j + 2, 64), w3 = __shfl(wv, j + 3, 64);
            float v0 = 0.f, v1 = 0.f, v2 = 0.f, v3 = 0.f;
            if (lane < OUT_CH) {
                v0 = bf2f(h[(size_t)s0 * OUT_CH + lane]);
                v1 = bf2f(h[(size_t)s1 * OUT_CH + lane]);
                v2 = bf2f(h[(size_t)s2 * OUT_CH + lane]);
                v3 = bf2f(h[(size_t)s3 * OUT_CH + lane]);
            }
            acc += v0 * w0 + v1 * w1 + v2 * w2 + v3 * w3;
        }
        for (; j < c; ++j) {
            int s0 = __shfl(sv, j, 64);
            float w0 = __shfl(wv, j, 64);
            if (lane < OUT_CH) acc += bf2f(h[(size_t)s0 * OUT_CH + lane]) * w0;
        }
    }
    int L = min(*ov_cnt, OV_CAP);
    for (int i = 0; i < L; ++i) {
        int4 e = ov[i];
        if (e.z == node && lane < OUT_CH)
            acc += bf2f(h[(size_t)e.x * OUT_CH + lane]) * __int_as_float(e.y);
    }
    float val = 0.f, v = -INFINITY;
    if (lane < OUT_CH) {
        val = acc + b[lane];
        v = val;
    }
#pragma unroll
    for (int off = 32; off; off >>= 1)
        v = fmaxf(v, __shfl_xor(v, off, 64));
    float ex = (lane < OUT_CH) ? expf(val - v) : 0.f;
#pragma unroll
    for (int off = 32; off; off >>= 1)
        ex += __shfl_xor(ex, off, 64);
    float ls = logf(ex);
    if (lane < OUT_CH) out[(size_t)node * OUT_CH + lane] = val - v - ls;
}

// ---------------------------------------------------------------------------
extern "C" void kernel_launch(void* const* d_in, const int* in_sizes, int n_in,
                              void* d_out, int out_size, void* d_ws, size_t ws_size,
                              hipStream_t stream) {
    const float* x   = (const float*)d_in[0];
    const int*  eidx = (const int*)d_in[1];
    const float* ew  = (const float*)d_in[2];
    const float* W1  = (const float*)d_in[3];
    const float* b1  = (const float*)d_in[4];
    const float* W2  = (const float*)d_in[5];
    const float* b2  = (const float*)d_in[6];
    const float* W3  = (const float*)d_in[7];
    const float* b3  = (const float*)d_in[8];
    const int* src = eidx;
    const int* dst = eidx + N_EDGES;
    float* out = (float*)d_out;

    short* region0 = (short*)d_ws;                          // xq(fp8) / h2p(fp8)
    short* region1 = region0 + (size_t)N_NODES * HID;       // aggX / h3p
    short* H1   = region1 + (size_t)N_NODES * IN_CH;
    short* H2   = H1 + (size_t)N_NODES * HID;
    short* Wt1  = H2 + (size_t)N_NODES * HID;
    short* Wt2  = Wt1 + HID * IN_CH;
    short* Wt3  = Wt2 + HID * HID;
    int*   cnt4    = (int*)(Wt3 + OUT_CH * HID);            // 4*N_NODES replica counters
    int*   ov_cnt  = cnt4 + 4 * N_NODES;                    // 1 (+3 pad)
    int*   cnt     = cnt4 + 4 * N_NODES + 4;                // N_NODES totals
    int2*  csr     = (int2*)(cnt + N_NODES);                // N_NODES*CAP int2
    int4*  ovbuf   = (int4*)(csr + (size_t)N_NODES * CAP);  // OV_CAP int4

    unsigned char* xq  = (unsigned char*)region0;           // fp8 chunk-major, 6.4 MB
    unsigned char* h2p = (unsigned char*)region0;           // fp8 chunk-major, 12.8 MB
    short* aggX = region1;
    short* h3p  = region1;

    dim3 blk(256);

    // ---- CSR build: memset + single-pass replicated fill + compact
    hipMemsetAsync(cnt4, 0, (4 * N_NODES + 1) * sizeof(int), stream);
    fill_fixed<<<(N_EDGES + 255) / 256, blk, 0, stream>>>(src, dst, ew, cnt4, csr, ovbuf, ov_cnt);
    compact_csr<<<(N_NODES + 15) / 16, blk, 0, stream>>>(cnt4, csr, cnt);

    // ---- weight + x casts
    {
        int tot = IN_CH * HID + HID * HID + HID * OUT_CH;
        wt_cast_all<<<(tot + 255) / 256, blk, 0, stream>>>(W1, W2, W3, Wt1, Wt2, Wt3);
    }
    cast_x_fp8<<<(N_NODES * IN_CH / 4 + 255) / 256, blk, 0, stream>>>(
        (const float4*)x, xq, N_NODES * IN_CH / 4);

    // ---- layer 1 (swapped): aggX = gather(xq); H1 = relu(aggX@W1 + b1)
    {
        dim3 grid((N_NODES + 15) / 16, 2);   // y = feature chunk (2 x 64)
        gather_x_fp8<<<grid, blk, 0, stream>>>(
            xq, cnt, csr, ovbuf, ov_cnt, (unsigned short*)aggX);
    }
    {
        dim3 grid((HID + 63) / 64, (N_NODES + 127) / 128);
        mfma_gemm<1><<<grid, blk, 0, stream>>>(aggX, Wt1, H1, N_NODES, IN_CH, HID, b1, 1);
    }

    // ---- layer 2: h2p = fp8(H1@W2) chunk-major ; H2 = relu(gather(h2p) + b2)
    {
        dim3 grid((HID + 63) / 64, (N_NODES + 127) / 128);
        mfma_gemm<3><<<grid, blk, 0, stream>>>(H1, Wt2, h2p, N_NODES, HID, HID, nullptr, 0);
    }
    {
        dim3 grid((N_NODES + 15) / 16, 4);   // y = feature chunk (4 x 64)
        gather_h_fp8<<<grid, blk, 0, stream>>>(
            h2p, cnt, csr, ovbuf, ov_cnt, b2, (unsigned short*)H2);
    }

    // ---- layer 3: h3p = H2@W3 (bf16) ; out = log_softmax(gather(h3p) + b3)
    {
        dim3 grid((OUT_CH + 63) / 64, (N_NODES + 127) / 128);
        mfma_gemm<1><<<grid, blk, 0, stream>>>(H2, Wt3, h3p, N_NODES, HID, OUT_CH, nullptr, 0);
    }
    gather_lsm<<<(N_NODES + 3) / 4, blk, 0, stream>>>(
        (const unsigned short*)h3p, cnt, csr, ovbuf, ov_cnt, b3, out, N_NODES);
}

// Round 19
// 301.028 us; speedup vs baseline: 1.1462x; 1.0421x over previous
//
#include <hip/hip_runtime.h>
#include <math.h>

#define N_NODES 50000
#define N_EDGES 800000
#define IN_CH 128
#define HID 256
#define OUT_CH 40

#define CAP 64          // fixed slots per node (deg~Poisson(16), max ~35)
#define OV_CAP 65536    // overflow safety net (correctness only)

// prologue grid partition (all parts independent)
#define FILL_BLOCKS ((N_EDGES + 255) / 256)                 // 3125
#define CASTX_BLOCKS ((N_NODES * IN_CH / 4 + 255) / 256)    // 6250
#define WT_TOT (IN_CH * HID + HID * HID + HID * OUT_CH)
#define WT_BLOCKS ((WT_TOT + 255) / 256)                    // 425

typedef __attribute__((ext_vector_type(8))) short short8;
typedef __attribute__((ext_vector_type(4))) float floatx4;
typedef __attribute__((ext_vector_type(2))) float floatx2;

typedef __attribute__((address_space(3))) void lds_void;
typedef const __attribute__((address_space(1))) void glb_void;

__device__ __forceinline__ unsigned short f2bf(float f) {
    unsigned int u = __float_as_uint(f);
    u += 0x7fff + ((u >> 16) & 1);
    return (unsigned short)(u >> 16);
}
__device__ __forceinline__ float bf2f(unsigned short h) {
    return __uint_as_float(((unsigned int)h) << 16);
}

// ---- fp8 e4m3fn (OCP) encode/decode (unbiased RNE) ----
__device__ __forceinline__ unsigned char f2fp8(float f) {
    f = fminf(448.f, fmaxf(-448.f, f));
    unsigned u = __float_as_uint(f);
    unsigned s = (u >> 24) & 0x80u;
    u &= 0x7fffffffu;
    if (u < 0x3c800000u) return (unsigned char)s;   // flush |f| < 2^-6
    unsigned r = u + 0x7FFFFu + ((u >> 20) & 1u);   // unbiased RNE
    unsigned em = (r >> 20) - 960u;
    return (unsigned char)(s | em);
}

__device__ __forceinline__ void fp8x4_to_f32x4(unsigned int q, float* o) {
#if defined(__has_builtin) && __has_builtin(__builtin_amdgcn_cvt_pk_f32_fp8)
    floatx2 lo = __builtin_amdgcn_cvt_pk_f32_fp8((int)q, false);
    floatx2 hi = __builtin_amdgcn_cvt_pk_f32_fp8((int)q, true);
    o[0] = lo.x; o[1] = lo.y; o[2] = hi.x; o[3] = hi.y;
#else
#pragma unroll
    for (int i = 0; i < 4; ++i) {
        unsigned b = (q >> (8 * i)) & 0xffu;
        unsigned em = b & 0x7fu;
        unsigned bits = em ? (((b & 0x80u) << 24) | ((em << 20) + (120u << 23)))
                           : ((b & 0x80u) << 24);
        o[i] = __uint_as_float(bits);
    }
#endif
}

// ====== FUSED PROLOGUE (r17): fill_fixed + cast_x_fp8 + wt_cast_all ========
// r3/r13/r17 A/B: fill ~50us floor is raw atomic+scattered-write throughput
// (replication null, fetch-cut null). During fill the chip is 99% VALU-idle /
// 86% HBM-idle -> overlap the independent cast work under it via grid
// partitioning instead of paying it sequentially (+2 launch gaps).
__global__ __launch_bounds__(256) void prologue(const int* __restrict__ src,
                                                const int* __restrict__ dst,
                                                const float* __restrict__ ew,
                                                int* __restrict__ cnt,
                                                int2* __restrict__ csr,
                                                int4* __restrict__ ov,
                                                int* __restrict__ ov_cnt,
                                                const float4* __restrict__ x4,
                                                unsigned char* __restrict__ xq,
                                                const float* __restrict__ W1,
                                                const float* __restrict__ W2,
                                                const float* __restrict__ W3,
                                                short* __restrict__ Wt1,
                                                short* __restrict__ Wt2,
                                                short* __restrict__ Wt3) {
    int b = blockIdx.x;
    if (b < FILL_BLOCKS) {
        // ---- CSR build: single pass, one edge per thread
        int e = b * 256 + threadIdx.x;
        if (e >= N_EDGES) return;
        int d = dst[e];
        int slot = atomicAdd(&cnt[d], 1);
        if (slot < CAP) {
            csr[(size_t)d * CAP + slot] = make_int2(src[e], __float_as_int(ew[e]));
        } else {
            int oi = atomicAdd(ov_cnt, 1);
            if (oi < OV_CAP)
                ov[oi] = make_int4(src[e], __float_as_int(ew[e]), d, 0);
        }
    } else if (b < FILL_BLOCKS + CASTX_BLOCKS) {
        // ---- x -> fp8 chunk-major xq[chunk][node][64] (3.2 MB/slice < L2)
        int i = (b - FILL_BLOCKS) * 256 + threadIdx.x;
        if (i >= N_NODES * IN_CH / 4) return;
        float4 v = x4[i];
        uchar4 q = make_uchar4(f2fp8(v.x), f2fp8(v.y), f2fp8(v.z), f2fp8(v.w));
        int n = i >> 5;
        int p = (i & 31) * 4;
        int chunk = p >> 6;
        size_t off = (size_t)chunk * ((size_t)N_NODES * 64) + (size_t)n * 64 + (p & 63);
        *(uchar4*)(xq + off) = q;
    } else {
        // ---- weight casts: Wt[m][k] = bf16(W[k][m])
        int idx = (b - FILL_BLOCKS - CASTX_BLOCKS) * 256 + threadIdx.x;
        const int n1 = IN_CH * HID, n2 = HID * HID, n3 = HID * OUT_CH;
        if (idx < n1) {
            int m = idx / IN_CH, k = idx - m * IN_CH;
            Wt1[idx] = (short)f2bf(W1[(size_t)k * HID + m]);
        } else if (idx < n1 + n2) {
            int j = idx - n1;
            int m = j / HID, k = j - m * HID;
            Wt2[j] = (short)f2bf(W2[(size_t)k * HID + m]);
        } else if (idx < n1 + n2 + n3) {
            int j = idx - n1 - n2;
            int m = j / HID, k = j - m * HID;
            Wt3[j] = (short)f2bf(W3[(size_t)k * OUT_CH + m]);
        }
    }
}

// -------- gather layer1: agg(x fp8) -> bf16, feature-chunked (r13 form) ----
// 16 lanes/node x 4 feats; blockIdx.y = chunk (2 chunks of 64 features).
__global__ __launch_bounds__(256) void gather_x_fp8(const unsigned char* __restrict__ xq,
                                                    const int* __restrict__ cnt,
                                                    const int2* __restrict__ csr,
                                                    const int4* __restrict__ ov,
                                                    const int* __restrict__ ov_cnt,
                                                    unsigned short* __restrict__ out) {
    int node = blockIdx.x * 16 + (threadIdx.x >> 4);
    int g = threadIdx.x & 15;
    int chunk = blockIdx.y;
    if (node >= N_NODES) return;
    const unsigned char* tab = xq + (size_t)chunk * ((size_t)N_NODES * 64);
    int beg = node * CAP;
    int end = beg + min(cnt[node], CAP);
    float a[4] = {};
    for (int base = beg; base < end; base += 16) {
        int c = min(16, end - base);
        int sv = 0; float wv = 0.f;
        if (g < c) {
            int2 iv = csr[base + g];
            sv = iv.x; wv = __int_as_float(iv.y);
        }
        int j = 0;
        for (; j + 4 <= c; j += 4) {
            int s0 = __shfl(sv, j, 16),     s1 = __shfl(sv, j + 1, 16);
            int s2 = __shfl(sv, j + 2, 16), s3 = __shfl(sv, j + 3, 16);
            float w0 = __shfl(wv, j, 16),     w1 = __shfl(wv, j + 1, 16);
            float w2 = __shfl(wv, j + 2, 16), w3 = __shfl(wv, j + 3, 16);
            unsigned q0 = *(const unsigned*)(tab + (size_t)s0 * 64 + g * 4);
            unsigned q1 = *(const unsigned*)(tab + (size_t)s1 * 64 + g * 4);
            unsigned q2 = *(const unsigned*)(tab + (size_t)s2 * 64 + g * 4);
            unsigned q3 = *(const unsigned*)(tab + (size_t)s3 * 64 + g * 4);
            float d0[4], d1[4], d2[4], d3[4];
            fp8x4_to_f32x4(q0, d0); fp8x4_to_f32x4(q1, d1);
            fp8x4_to_f32x4(q2, d2); fp8x4_to_f32x4(q3, d3);
#pragma unroll
            for (int t = 0; t < 4; ++t)
                a[t] += d0[t] * w0 + d1[t] * w1 + d2[t] * w2 + d3[t] * w3;
        }
        for (; j < c; ++j) {
            int s0 = __shfl(sv, j, 16);
            float w0 = __shfl(wv, j, 16);
            unsigned q0 = *(const unsigned*)(tab + (size_t)s0 * 64 + g * 4);
            float d0[4];
            fp8x4_to_f32x4(q0, d0);
#pragma unroll
            for (int t = 0; t < 4; ++t) a[t] += d0[t] * w0;
        }
    }
    int L = min(*ov_cnt, OV_CAP);
    for (int i = 0; i < L; ++i) {
        int4 e = ov[i];
        if (e.z == node) {
            float w0 = __int_as_float(e.y);
            unsigned q0 = *(const unsigned*)(tab + (size_t)e.x * 64 + g * 4);
            float d0[4];
            fp8x4_to_f32x4(q0, d0);
#pragma unroll
            for (int t = 0; t < 4; ++t) a[t] += d0[t] * w0;
        }
    }
    ushort4 o = make_ushort4(f2bf(a[0]), f2bf(a[1]), f2bf(a[2]), f2bf(a[3]));
    *(ushort4*)(out + (size_t)node * 128 + chunk * 64 + g * 4) = o;
}

// ---- gather layer2: agg(h fp8 chunk-major) -> bias+relu -> bf16 (r13 form) -
__global__ __launch_bounds__(256) void gather_h_fp8(const unsigned char* __restrict__ h,
                                                    const int* __restrict__ cnt,
                                                    const int2* __restrict__ csr,
                                                    const int4* __restrict__ ov,
                                                    const int* __restrict__ ov_cnt,
                                                    const float* __restrict__ bias,
                                                    unsigned short* __restrict__ out) {
    int node = blockIdx.x * 16 + (threadIdx.x >> 4);
    int g = threadIdx.x & 15;
    int chunk = blockIdx.y;
    if (node >= N_NODES) return;
    const unsigned char* tab = h + (size_t)chunk * ((size_t)N_NODES * 64);
    int beg = node * CAP;
    int end = beg + min(cnt[node], CAP);
    float acc[4] = {};
    for (int base = beg; base < end; base += 16) {
        int c = min(16, end - base);
        int sv = 0; float wv = 0.f;
        if (g < c) {
            int2 iv = csr[base + g];
            sv = iv.x; wv = __int_as_float(iv.y);
        }
        int j = 0;
        for (; j + 4 <= c; j += 4) {
            int s0 = __shfl(sv, j, 16),     s1 = __shfl(sv, j + 1, 16);
            int s2 = __shfl(sv, j + 2, 16), s3 = __shfl(sv, j + 3, 16);
            float w0 = __shfl(wv, j, 16),     w1 = __shfl(wv, j + 1, 16);
            float w2 = __shfl(wv, j + 2, 16), w3 = __shfl(wv, j + 3, 16);
            unsigned q0 = *(const unsigned*)(tab + (size_t)s0 * 64 + g * 4);
            unsigned q1 = *(const unsigned*)(tab + (size_t)s1 * 64 + g * 4);
            unsigned q2 = *(const unsigned*)(tab + (size_t)s2 * 64 + g * 4);
            unsigned q3 = *(const unsigned*)(tab + (size_t)s3 * 64 + g * 4);
            float d0[4], d1[4], d2[4], d3[4];
            fp8x4_to_f32x4(q0, d0); fp8x4_to_f32x4(q1, d1);
            fp8x4_to_f32x4(q2, d2); fp8x4_to_f32x4(q3, d3);
#pragma unroll
            for (int t = 0; t < 4; ++t)
                acc[t] += d0[t] * w0 + d1[t] * w1 + d2[t] * w2 + d3[t] * w3;
        }
        for (; j < c; ++j) {
            int s0 = __shfl(sv, j, 16);
            float w0 = __shfl(wv, j, 16);
            unsigned q0 = *(const unsigned*)(tab + (size_t)s0 * 64 + g * 4);
            float d0[4];
            fp8x4_to_f32x4(q0, d0);
#pragma unroll
            for (int t = 0; t < 4; ++t) acc[t] += d0[t] * w0;
        }
    }
    int L = min(*ov_cnt, OV_CAP);
    for (int i = 0; i < L; ++i) {
        int4 e = ov[i];
        if (e.z == node) {
            float w0 = __int_as_float(e.y);
            unsigned q0 = *(const unsigned*)(tab + (size_t)e.x * 64 + g * 4);
            float d0[4];
            fp8x4_to_f32x4(q0, d0);
#pragma unroll
            for (int t = 0; t < 4; ++t) acc[t] += d0[t] * w0;
        }
    }
    ushort4 o;
    {
        float r0 = fmaxf(acc[0] + bias[chunk * 64 + g * 4 + 0], 0.f);
        float r1 = fmaxf(acc[1] + bias[chunk * 64 + g * 4 + 1], 0.f);
        float r2 = fmaxf(acc[2] + bias[chunk * 64 + g * 4 + 2], 0.f);
        float r3 = fmaxf(acc[3] + bias[chunk * 64 + g * 4 + 3], 0.f);
        o = make_ushort4(f2bf(r0), f2bf(r1), f2bf(r2), f2bf(r3));
    }
    *(ushort4*)(out + (size_t)node * 256 + chunk * 64 + g * 4) = o;
}

// --------------- bf16 MFMA GEMM: C[N,M] = A[N,K] @ Wt[M,K]^T ---------------
// BM=128, BN=64, BK=32; 4 waves (2x2). Staging via global_load_lds width=16.
// OUT_MODE: 0=f32, 1=bf16, 2=fp8 row-major, 3=fp8 CHUNK-MAJOR.
template <int OUT_MODE>
__global__ __launch_bounds__(256) void mfma_gemm(const short* __restrict__ A,
                                                 const short* __restrict__ Wt,
                                                 void* __restrict__ Cout,
                                                 int N, int K, int M,
                                                 const float* __restrict__ bias,
                                                 int act) {
    __shared__ short As[128 * 32];
    __shared__ short Bs[64 * 32];
    const int tid = threadIdx.x;
    const int lane = tid & 63;
    const int wave = tid >> 6;
    const int wr = wave >> 1, wc = wave & 1;
    const int row0 = blockIdx.y * 128;
    const int col0 = blockIdx.x * 64;

    floatx4 acc[4][2];
#pragma unroll
    for (int t = 0; t < 4; ++t)
#pragma unroll
        for (int u = 0; u < 2; ++u) acc[t][u] = (floatx4){0.f, 0.f, 0.f, 0.f};

    for (int k0 = 0; k0 < K; k0 += 32) {
#pragma unroll
        for (int j = 0; j < 2; ++j) {
            int c = wave * 128 + j * 64 + lane;
            int r = c >> 2, cc = c & 3;
            int gr = min(row0 + r, N - 1);
            const short* gp = A + (size_t)gr * K + k0 + ((cc ^ ((r >> 1) & 3)) << 3);
            __builtin_amdgcn_global_load_lds(
                (glb_void*)gp,
                (lds_void*)(As + (size_t)(wave * 128 + j * 64) * 8), 16, 0, 0);
        }
        {
            int c = wave * 64 + lane;
            int r = c >> 2, cc = c & 3;
            int gn = min(col0 + r, M - 1);
            const short* gp = Wt + (size_t)gn * K + k0 + ((cc ^ ((r >> 1) & 3)) << 3);
            __builtin_amdgcn_global_load_lds(
                (glb_void*)gp,
                (lds_void*)(Bs + (size_t)(wave * 64) * 8), 16, 0, 0);
        }
        __syncthreads();

        short8 bf[2];
#pragma unroll
        for (int u = 0; u < 2; ++u) {
            int n = wc * 32 + u * 16 + (lane & 15);
            int ch = (lane >> 4) ^ ((n >> 1) & 3);
            bf[u] = *(const short8*)&Bs[n * 32 + (ch << 3)];
        }
#pragma unroll
        for (int t = 0; t < 4; ++t) {
            int r = wr * 64 + t * 16 + (lane & 15);
            int ch = (lane >> 4) ^ ((r >> 1) & 3);
            short8 af = *(const short8*)&As[r * 32 + (ch << 3)];
            acc[t][0] = __builtin_amdgcn_mfma_f32_16x16x32_bf16(af, bf[0], acc[t][0], 0, 0, 0);
            acc[t][1] = __builtin_amdgcn_mfma_f32_16x16x32_bf16(af, bf[1], acc[t][1], 0, 0, 0);
        }
        __syncthreads();
    }

#pragma unroll
    for (int t = 0; t < 4; ++t) {
#pragma unroll
        for (int u = 0; u < 2; ++u) {
            int gcol = col0 + wc * 32 + u * 16 + (lane & 15);
            if (gcol >= M) continue;
            float bv = bias ? bias[gcol] : 0.f;
#pragma unroll
            for (int reg = 0; reg < 4; ++reg) {
                int grow = row0 + wr * 64 + t * 16 + (lane >> 4) * 4 + reg;
                if (grow >= N) continue;
                float v = acc[t][u][reg] + bv;
                if (act) v = fmaxf(v, 0.f);
                if (OUT_MODE == 1)
                    ((unsigned short*)Cout)[(size_t)grow * M + gcol] = f2bf(v);
                else if (OUT_MODE == 2)
                    ((unsigned char*)Cout)[(size_t)grow * M + gcol] = f2fp8(v);
                else if (OUT_MODE == 3)
                    ((unsigned char*)Cout)[(size_t)(gcol >> 6) * ((size_t)N * 64) +
                                           (size_t)grow * 64 + (gcol & 63)] = f2fp8(v);
                else
                    ((float*)Cout)[(size_t)grow * M + gcol] = v;
            }
        }
    }
}

// ---- final: gather bf16 40-wide rows + bias + log_softmax (r13 form) ------
__global__ __launch_bounds__(256) void gather_lsm(const unsigned short* __restrict__ h,
                                                  const int* __restrict__ cnt,
                                                  const int2* __restrict__ csr,
                                                  const int4* __restrict__ ov,
                                                  const int* __restrict__ ov_cnt,
                                                  const float* __restrict__ b,
                                                  float* __restrict__ out, int n) {
    int wave = threadIdx.x >> 6;
    int lane = threadIdx.x & 63;
    int node = blockIdx.x * 4 + wave;
    if (node >= n) return;
    int beg = node * CAP;
    int end = beg + min(cnt[node], CAP);
    float acc = 0.f;
    for (int base = beg; base < end; base += 64) {
        int c = min(64, end - base);
        int sv = 0; float wv = 0.f;
        if (lane < c) {
            int2 iv = csr[base + lane];
            sv = iv.x; wv = __int_as_float(iv.y);
        }
        int j = 0;
        for (; j + 4 <= c; j += 4) {
            int s0 = __shfl(sv, j, 64),     s1 = __shfl(sv, j + 1, 64);
            int s2 = __shfl(sv, j + 2, 64), s3 = __shfl(sv, j + 3, 64);
            float w0 = __shfl(wv, j, 64),     w1 = __shfl(wv, j + 1, 64);
            float w2 = __shfl(wv, j + 2, 64), w3 = __shfl(wv, j + 3, 64);
            float v0 = 0.f, v1 = 0.f, v2 = 0.f, v3 = 0.f;
            if (lane < OUT_CH) {
                v0 = bf2f(h[(size_t)s0 * OUT_CH + lane]);
                v1 = bf2f(h[(size_t)s1 * OUT_CH + lane]);
                v2 = bf2f(h[(size_t)s2 * OUT_CH + lane]);
                v3 = bf2f(h[(size_t)s3 * OUT_CH + lane]);
            }
            acc += v0 * w0 + v1 * w1 + v2 * w2 + v3 * w3;
        }
        for (; j < c; ++j) {
            int s0 = __shfl(sv, j, 64);
            float w0 = __shfl(wv, j, 64);
            if (lane < OUT_CH) acc += bf2f(h[(size_t)s0 * OUT_CH + lane]) * w0;
        }
    }
    int L = min(*ov_cnt, OV_CAP);
    for (int i = 0; i < L; ++i) {
        int4 e = ov[i];
        if (e.z == node && lane < OUT_CH)
            acc += bf2f(h[(size_t)e.x * OUT_CH + lane]) * __int_as_float(e.y);
    }
    float val = 0.f, v = -INFINITY;
    if (lane < OUT_CH) {
        val = acc + b[lane];
        v = val;
    }
#pragma unroll
    for (int off = 32; off; off >>= 1)
        v = fmaxf(v, __shfl_xor(v, off, 64));
    float ex = (lane < OUT_CH) ? expf(val - v) : 0.f;
#pragma unroll
    for (int off = 32; off; off >>= 1)
        ex += __shfl_xor(ex, off, 64);
    float ls = logf(ex);
    if (lane < OUT_CH) out[(size_t)node * OUT_CH + lane] = val - v - ls;
}

// ---------------------------------------------------------------------------
extern "C" void kernel_launch(void* const* d_in, const int* in_sizes, int n_in,
                              void* d_out, int out_size, void* d_ws, size_t ws_size,
                              hipStream_t stream) {
    const float* x   = (const float*)d_in[0];
    const int*  eidx = (const int*)d_in[1];
    const float* ew  = (const float*)d_in[2];
    const float* W1  = (const float*)d_in[3];
    const float* b1  = (const float*)d_in[4];
    const float* W2  = (const float*)d_in[5];
    const float* b2  = (const float*)d_in[6];
    const float* W3  = (const float*)d_in[7];
    const float* b3  = (const float*)d_in[8];
    const int* src = eidx;
    const int* dst = eidx + N_EDGES;
    float* out = (float*)d_out;

    short* region0 = (short*)d_ws;                          // xq(fp8) / h2p(fp8)
    short* region1 = region0 + (size_t)N_NODES * HID;       // aggX / h3p
    short* H1   = region1 + (size_t)N_NODES * IN_CH;
    short* H2   = H1 + (size_t)N_NODES * HID;
    short* Wt1  = H2 + (size_t)N_NODES * HID;
    short* Wt2  = Wt1 + HID * IN_CH;
    short* Wt3  = Wt2 + HID * HID;
    int*   cnt     = (int*)(Wt3 + OUT_CH * HID);            // N_NODES + ov_cnt
    int*   ov_cnt  = cnt + N_NODES;
    int2*  csr     = (int2*)(cnt + N_NODES + 2);            // N_NODES*CAP int2
    int4*  ovbuf   = (int4*)(csr + (size_t)N_NODES * CAP);  // OV_CAP int4

    unsigned char* xq  = (unsigned char*)region0;           // fp8 chunk-major, 6.4 MB
    unsigned char* h2p = (unsigned char*)region0;           // fp8 chunk-major, 12.8 MB
    short* aggX = region1;
    short* h3p  = region1;

    dim3 blk(256);

    // ---- fused prologue: CSR fill + x cast + weight casts (independent parts)
    hipMemsetAsync(cnt, 0, (N_NODES + 1) * sizeof(int), stream);
    prologue<<<FILL_BLOCKS + CASTX_BLOCKS + WT_BLOCKS, blk, 0, stream>>>(
        src, dst, ew, cnt, csr, ovbuf, ov_cnt,
        (const float4*)x, xq, W1, W2, W3, Wt1, Wt2, Wt3);

    // ---- layer 1 (swapped): aggX = gather(xq); H1 = relu(aggX@W1 + b1)
    {
        dim3 grid((N_NODES + 15) / 16, 2);   // y = feature chunk (2 x 64)
        gather_x_fp8<<<grid, blk, 0, stream>>>(
            xq, cnt, csr, ovbuf, ov_cnt, (unsigned short*)aggX);
    }
    {
        dim3 grid((HID + 63) / 64, (N_NODES + 127) / 128);
        mfma_gemm<1><<<grid, blk, 0, stream>>>(aggX, Wt1, H1, N_NODES, IN_CH, HID, b1, 1);
    }

    // ---- layer 2: h2p = fp8(H1@W2) chunk-major ; H2 = relu(gather(h2p) + b2)
    {
        dim3 grid((HID + 63) / 64, (N_NODES + 127) / 128);
        mfma_gemm<3><<<grid, blk, 0, stream>>>(H1, Wt2, h2p, N_NODES, HID, HID, nullptr, 0);
    }
    {
        dim3 grid((N_NODES + 15) / 16, 4);   // y = feature chunk (4 x 64)
        gather_h_fp8<<<grid, blk, 0, stream>>>(
            h2p, cnt, csr, ovbuf, ov_cnt, b2, (unsigned short*)H2);
    }

    // ---- layer 3: h3p = H2@W3 (bf16) ; out = log_softmax(gather(h3p) + b3)
    {
        dim3 grid((OUT_CH + 63) / 64, (N_NODES + 127) / 128);
        mfma_gemm<1><<<grid, blk, 0, stream>>>(H2, Wt3, h3p, N_NODES, HID, OUT_CH, nullptr, 0);
    }
    gather_lsm<<<(N_NODES + 3) / 4, blk, 0, stream>>>(
        (const unsigned short*)h3p, cnt, csr, ovbuf, ov_cnt, b3, out, N_NODES);
}

// Round 22
// 297.277 us; speedup vs baseline: 1.1607x; 1.0126x over previous
//
#include <hip/hip_runtime.h>
#include <math.h>

#define N_NODES 50000
#define N_EDGES 800000
#define IN_CH 128
#define HID 256
#define OUT_CH 40

#define CAP 64          // fixed slots per node (deg~Poisson(16), max ~35)
#define OV_CAP 65536    // overflow safety net (correctness only)

// prologue grid partition (all parts independent)
#define FILL_BLOCKS ((N_EDGES + 255) / 256)                 // 3125
#define CASTX_BLOCKS ((N_NODES * IN_CH / 4 + 255) / 256)    // 6250
#define WT_TOT (IN_CH * HID + HID * HID + HID * OUT_CH)
#define WT_BLOCKS ((WT_TOT + 255) / 256)                    // 425

typedef __attribute__((ext_vector_type(8))) short short8;
typedef __attribute__((ext_vector_type(4))) float floatx4;
typedef __attribute__((ext_vector_type(2))) float floatx2;

typedef __attribute__((address_space(3))) void lds_void;
typedef const __attribute__((address_space(1))) void glb_void;

__device__ __forceinline__ unsigned short f2bf(float f) {
    unsigned int u = __float_as_uint(f);
    u += 0x7fff + ((u >> 16) & 1);
    return (unsigned short)(u >> 16);
}
__device__ __forceinline__ float bf2f(unsigned short h) {
    return __uint_as_float(((unsigned int)h) << 16);
}

// ---- fp8 e4m3fn (OCP) encode/decode (unbiased RNE) ----
__device__ __forceinline__ unsigned char f2fp8(float f) {
    f = fminf(448.f, fmaxf(-448.f, f));
    unsigned u = __float_as_uint(f);
    unsigned s = (u >> 24) & 0x80u;
    u &= 0x7fffffffu;
    if (u < 0x3c800000u) return (unsigned char)s;   // flush |f| < 2^-6
    unsigned r = u + 0x7FFFFu + ((u >> 20) & 1u);   // unbiased RNE
    unsigned em = (r >> 20) - 960u;
    return (unsigned char)(s | em);
}

__device__ __forceinline__ void fp8x4_to_f32x4(unsigned int q, float* o) {
#if defined(__has_builtin) && __has_builtin(__builtin_amdgcn_cvt_pk_f32_fp8)
    floatx2 lo = __builtin_amdgcn_cvt_pk_f32_fp8((int)q, false);
    floatx2 hi = __builtin_amdgcn_cvt_pk_f32_fp8((int)q, true);
    o[0] = lo.x; o[1] = lo.y; o[2] = hi.x; o[3] = hi.y;
#else
#pragma unroll
    for (int i = 0; i < 4; ++i) {
        unsigned b = (q >> (8 * i)) & 0xffu;
        unsigned em = b & 0x7fu;
        unsigned bits = em ? (((b & 0x80u) << 24) | ((em << 20) + (120u << 23)))
                           : ((b & 0x80u) << 24);
        o[i] = __uint_as_float(bits);
    }
#endif
}

// ====== FUSED PROLOGUE (r17): fill_fixed + cast_x_fp8 + wt_cast_all ========
// r3/r13/r17 A/B: fill ~50us floor is raw atomic+scattered-write throughput.
// During fill the chip is idle -> overlap the independent cast work under it.
// MEASURED r19: 50-53us, end-to-end 313.7 -> 301.0.
__global__ __launch_bounds__(256) void prologue(const int* __restrict__ src,
                                                const int* __restrict__ dst,
                                                const float* __restrict__ ew,
                                                int* __restrict__ cnt,
                                                int2* __restrict__ csr,
                                                int4* __restrict__ ov,
                                                int* __restrict__ ov_cnt,
                                                const float4* __restrict__ x4,
                                                unsigned char* __restrict__ xq,
                                                const float* __restrict__ W1,
                                                const float* __restrict__ W2,
                                                const float* __restrict__ W3,
                                                short* __restrict__ Wt1,
                                                short* __restrict__ Wt2,
                                                short* __restrict__ Wt3) {
    int b = blockIdx.x;
    if (b < FILL_BLOCKS) {
        // ---- CSR build: single pass, one edge per thread
        int e = b * 256 + threadIdx.x;
        if (e >= N_EDGES) return;
        int d = dst[e];
        int slot = atomicAdd(&cnt[d], 1);
        if (slot < CAP) {
            csr[(size_t)d * CAP + slot] = make_int2(src[e], __float_as_int(ew[e]));
        } else {
            int oi = atomicAdd(ov_cnt, 1);
            if (oi < OV_CAP)
                ov[oi] = make_int4(src[e], __float_as_int(ew[e]), d, 0);
        }
    } else if (b < FILL_BLOCKS + CASTX_BLOCKS) {
        // ---- x -> fp8 chunk-major xq[chunk][node][64] (3.2 MB/slice < L2)
        int i = (b - FILL_BLOCKS) * 256 + threadIdx.x;
        if (i >= N_NODES * IN_CH / 4) return;
        float4 v = x4[i];
        uchar4 q = make_uchar4(f2fp8(v.x), f2fp8(v.y), f2fp8(v.z), f2fp8(v.w));
        int n = i >> 5;
        int p = (i & 31) * 4;
        int chunk = p >> 6;
        size_t off = (size_t)chunk * ((size_t)N_NODES * 64) + (size_t)n * 64 + (p & 63);
        *(uchar4*)(xq + off) = q;
    } else {
        // ---- weight casts: Wt[m][k] = bf16(W[k][m])
        int idx = (b - FILL_BLOCKS - CASTX_BLOCKS) * 256 + threadIdx.x;
        const int n1 = IN_CH * HID, n2 = HID * HID, n3 = HID * OUT_CH;
        if (idx < n1) {
            int m = idx / IN_CH, k = idx - m * IN_CH;
            Wt1[idx] = (short)f2bf(W1[(size_t)k * HID + m]);
        } else if (idx < n1 + n2) {
            int j = idx - n1;
            int m = j / HID, k = j - m * HID;
            Wt2[j] = (short)f2bf(W2[(size_t)k * HID + m]);
        } else if (idx < n1 + n2 + n3) {
            int j = idx - n1 - n2;
            int m = j / HID, k = j - m * HID;
            Wt3[j] = (short)f2bf(W3[(size_t)k * OUT_CH + m]);
        }
    }
}

// -------- gather layer1: agg(x fp8) -> bf16, feature-chunked (r13 form) ----
// 16 lanes/node x 4 feats; blockIdx.y = chunk (2 chunks of 64 features).
__global__ __launch_bounds__(256) void gather_x_fp8(const unsigned char* __restrict__ xq,
                                                    const int* __restrict__ cnt,
                                                    const int2* __restrict__ csr,
                                                    const int4* __restrict__ ov,
                                                    const int* __restrict__ ov_cnt,
                                                    unsigned short* __restrict__ out) {
    int node = blockIdx.x * 16 + (threadIdx.x >> 4);
    int g = threadIdx.x & 15;
    int chunk = blockIdx.y;
    if (node >= N_NODES) return;
    const unsigned char* tab = xq + (size_t)chunk * ((size_t)N_NODES * 64);
    int beg = node * CAP;
    int end = beg + min(cnt[node], CAP);
    float a[4] = {};
    for (int base = beg; base < end; base += 16) {
        int c = min(16, end - base);
        int sv = 0; float wv = 0.f;
        if (g < c) {
            int2 iv = csr[base + g];
            sv = iv.x; wv = __int_as_float(iv.y);
        }
        int j = 0;
        for (; j + 4 <= c; j += 4) {
            int s0 = __shfl(sv, j, 16),     s1 = __shfl(sv, j + 1, 16);
            int s2 = __shfl(sv, j + 2, 16), s3 = __shfl(sv, j + 3, 16);
            float w0 = __shfl(wv, j, 16),     w1 = __shfl(wv, j + 1, 16);
            float w2 = __shfl(wv, j + 2, 16), w3 = __shfl(wv, j + 3, 16);
            unsigned q0 = *(const unsigned*)(tab + (size_t)s0 * 64 + g * 4);
            unsigned q1 = *(const unsigned*)(tab + (size_t)s1 * 64 + g * 4);
            unsigned q2 = *(const unsigned*)(tab + (size_t)s2 * 64 + g * 4);
            unsigned q3 = *(const unsigned*)(tab + (size_t)s3 * 64 + g * 4);
            float d0[4], d1[4], d2[4], d3[4];
            fp8x4_to_f32x4(q0, d0); fp8x4_to_f32x4(q1, d1);
            fp8x4_to_f32x4(q2, d2); fp8x4_to_f32x4(q3, d3);
#pragma unroll
            for (int t = 0; t < 4; ++t)
                a[t] += d0[t] * w0 + d1[t] * w1 + d2[t] * w2 + d3[t] * w3;
        }
        for (; j < c; ++j) {
            int s0 = __shfl(sv, j, 16);
            float w0 = __shfl(wv, j, 16);
            unsigned q0 = *(const unsigned*)(tab + (size_t)s0 * 64 + g * 4);
            float d0[4];
            fp8x4_to_f32x4(q0, d0);
#pragma unroll
            for (int t = 0; t < 4; ++t) a[t] += d0[t] * w0;
        }
    }
    int L = min(*ov_cnt, OV_CAP);
    for (int i = 0; i < L; ++i) {
        int4 e = ov[i];
        if (e.z == node) {
            float w0 = __int_as_float(e.y);
            unsigned q0 = *(const unsigned*)(tab + (size_t)e.x * 64 + g * 4);
            float d0[4];
            fp8x4_to_f32x4(q0, d0);
#pragma unroll
            for (int t = 0; t < 4; ++t) a[t] += d0[t] * w0;
        }
    }
    ushort4 o = make_ushort4(f2bf(a[0]), f2bf(a[1]), f2bf(a[2]), f2bf(a[3]));
    *(ushort4*)(out + (size_t)node * 128 + chunk * 64 + g * 4) = o;
}

// ---- gather layer2 (r19): 8 lanes/node x 8 feats, uint2 loads -------------
// r16 profile: gather_h partially VALU-bound (49% busy). 8-lane groups halve
// the shuffle+address work per accumulated value: one 8B uint2 load covers 8
// features, 32 nodes/block. Same 64B/edge/chunk traffic.
__global__ __launch_bounds__(256) void gather_h_fp8(const unsigned char* __restrict__ h,
                                                    const int* __restrict__ cnt,
                                                    const int2* __restrict__ csr,
                                                    const int4* __restrict__ ov,
                                                    const int* __restrict__ ov_cnt,
                                                    const float* __restrict__ bias,
                                                    unsigned short* __restrict__ out) {
    int node = blockIdx.x * 32 + (threadIdx.x >> 3);
    int g = threadIdx.x & 7;
    int chunk = blockIdx.y;
    if (node >= N_NODES) return;
    const unsigned char* tab = h + (size_t)chunk * ((size_t)N_NODES * 64);
    int beg = node * CAP;
    int end = beg + min(cnt[node], CAP);
    float acc[8] = {};
    for (int base = beg; base < end; base += 8) {
        int c = min(8, end - base);
        int sv = 0; float wv = 0.f;
        if (g < c) {
            int2 iv = csr[base + g];
            sv = iv.x; wv = __int_as_float(iv.y);
        }
        int j = 0;
        for (; j + 4 <= c; j += 4) {
            int s0 = __shfl(sv, j, 8),     s1 = __shfl(sv, j + 1, 8);
            int s2 = __shfl(sv, j + 2, 8), s3 = __shfl(sv, j + 3, 8);
            float w0 = __shfl(wv, j, 8),     w1 = __shfl(wv, j + 1, 8);
            float w2 = __shfl(wv, j + 2, 8), w3 = __shfl(wv, j + 3, 8);
            uint2 q0 = *(const uint2*)(tab + (size_t)s0 * 64 + g * 8);
            uint2 q1 = *(const uint2*)(tab + (size_t)s1 * 64 + g * 8);
            uint2 q2 = *(const uint2*)(tab + (size_t)s2 * 64 + g * 8);
            uint2 q3 = *(const uint2*)(tab + (size_t)s3 * 64 + g * 8);
            float d0[8], d1[8], d2[8], d3[8];
            fp8x4_to_f32x4(q0.x, d0); fp8x4_to_f32x4(q0.y, d0 + 4);
            fp8x4_to_f32x4(q1.x, d1); fp8x4_to_f32x4(q1.y, d1 + 4);
            fp8x4_to_f32x4(q2.x, d2); fp8x4_to_f32x4(q2.y, d2 + 4);
            fp8x4_to_f32x4(q3.x, d3); fp8x4_to_f32x4(q3.y, d3 + 4);
#pragma unroll
            for (int t = 0; t < 8; ++t)
                acc[t] += d0[t] * w0 + d1[t] * w1 + d2[t] * w2 + d3[t] * w3;
        }
        for (; j < c; ++j) {
            int s0 = __shfl(sv, j, 8);
            float w0 = __shfl(wv, j, 8);
            uint2 q0 = *(const uint2*)(tab + (size_t)s0 * 64 + g * 8);
            float d0[8];
            fp8x4_to_f32x4(q0.x, d0); fp8x4_to_f32x4(q0.y, d0 + 4);
#pragma unroll
            for (int t = 0; t < 8; ++t) acc[t] += d0[t] * w0;
        }
    }
    int L = min(*ov_cnt, OV_CAP);
    for (int i = 0; i < L; ++i) {
        int4 e = ov[i];
        if (e.z == node) {
            float w0 = __int_as_float(e.y);
            uint2 q0 = *(const uint2*)(tab + (size_t)e.x * 64 + g * 8);
            float d0[8];
            fp8x4_to_f32x4(q0.x, d0); fp8x4_to_f32x4(q0.y, d0 + 4);
#pragma unroll
            for (int t = 0; t < 8; ++t) acc[t] += d0[t] * w0;
        }
    }
    short8 o;
#pragma unroll
    for (int t = 0; t < 8; ++t) {
        float r = fmaxf(acc[t] + bias[chunk * 64 + g * 8 + t], 0.f);
        o[t] = (short)f2bf(r);
    }
    *(short8*)(out + (size_t)node * 256 + chunk * 64 + g * 8) = o;
}

// --------------- bf16 MFMA GEMM: C[N,M] = A[N,K] @ Wt[M,K]^T ---------------
// BM=128, BN=64, BK=32; 4 waves (2x2). Staging via global_load_lds width=16.
// OUT_MODE: 0=f32, 1=bf16, 2=fp8 row-major, 3=fp8 CHUNK-MAJOR.
template <int OUT_MODE>
__global__ __launch_bounds__(256) void mfma_gemm(const short* __restrict__ A,
                                                 const short* __restrict__ Wt,
                                                 void* __restrict__ Cout,
                                                 int N, int K, int M,
                                                 const float* __restrict__ bias,
                                                 int act) {
    __shared__ short As[128 * 32];
    __shared__ short Bs[64 * 32];
    const int tid = threadIdx.x;
    const int lane = tid & 63;
    const int wave = tid >> 6;
    const int wr = wave >> 1, wc = wave & 1;
    const int row0 = blockIdx.y * 128;
    const int col0 = blockIdx.x * 64;

    floatx4 acc[4][2];
#pragma unroll
    for (int t = 0; t < 4; ++t)
#pragma unroll
        for (int u = 0; u < 2; ++u) acc[t][u] = (floatx4){0.f, 0.f, 0.f, 0.f};

    for (int k0 = 0; k0 < K; k0 += 32) {
#pragma unroll
        for (int j = 0; j < 2; ++j) {
            int c = wave * 128 + j * 64 + lane;
            int r = c >> 2, cc = c & 3;
            int gr = min(row0 + r, N - 1);
            const short* gp = A + (size_t)gr * K + k0 + ((cc ^ ((r >> 1) & 3)) << 3);
            __builtin_amdgcn_global_load_lds(
                (glb_void*)gp,
                (lds_void*)(As + (size_t)(wave * 128 + j * 64) * 8), 16, 0, 0);
        }
        {
            int c = wave * 64 + lane;
            int r = c >> 2, cc = c & 3;
            int gn = min(col0 + r, M - 1);
            const short* gp = Wt + (size_t)gn * K + k0 + ((cc ^ ((r >> 1) & 3)) << 3);
            __builtin_amdgcn_global_load_lds(
                (glb_void*)gp,
                (lds_void*)(Bs + (size_t)(wave * 64) * 8), 16, 0, 0);
        }
        __syncthreads();

        short8 bf[2];
#pragma unroll
        for (int u = 0; u < 2; ++u) {
            int n = wc * 32 + u * 16 + (lane & 15);
            int ch = (lane >> 4) ^ ((n >> 1) & 3);
            bf[u] = *(const short8*)&Bs[n * 32 + (ch << 3)];
        }
#pragma unroll
        for (int t = 0; t < 4; ++t) {
            int r = wr * 64 + t * 16 + (lane & 15);
            int ch = (lane >> 4) ^ ((r >> 1) & 3);
            short8 af = *(const short8*)&As[r * 32 + (ch << 3)];
            acc[t][0] = __builtin_amdgcn_mfma_f32_16x16x32_bf16(af, bf[0], acc[t][0], 0, 0, 0);
            acc[t][1] = __builtin_amdgcn_mfma_f32_16x16x32_bf16(af, bf[1], acc[t][1], 0, 0, 0);
        }
        __syncthreads();
    }

#pragma unroll
    for (int t = 0; t < 4; ++t) {
#pragma unroll
        for (int u = 0; u < 2; ++u) {
            int gcol = col0 + wc * 32 + u * 16 + (lane & 15);
            if (gcol >= M) continue;
            float bv = bias ? bias[gcol] : 0.f;
#pragma unroll
            for (int reg = 0; reg < 4; ++reg) {
                int grow = row0 + wr * 64 + t * 16 + (lane >> 4) * 4 + reg;
                if (grow >= N) continue;
                float v = acc[t][u][reg] + bv;
                if (act) v = fmaxf(v, 0.f);
                if (OUT_MODE == 1)
                    ((unsigned short*)Cout)[(size_t)grow * M + gcol] = f2bf(v);
                else if (OUT_MODE == 2)
                    ((unsigned char*)Cout)[(size_t)grow * M + gcol] = f2fp8(v);
                else if (OUT_MODE == 3)
                    ((unsigned char*)Cout)[(size_t)(gcol >> 6) * ((size_t)N * 64) +
                                           (size_t)grow * 64 + (gcol & 63)] = f2fp8(v);
                else
                    ((float*)Cout)[(size_t)grow * M + gcol] = v;
            }
        }
    }
}

// ---- final: gather bf16 40-wide rows + bias + log_softmax (r13 form) ------
__global__ __launch_bounds__(256) void gather_lsm(const unsigned short* __restrict__ h,
                                                  const int* __restrict__ cnt,
                                                  const int2* __restrict__ csr,
                                                  const int4* __restrict__ ov,
                                                  const int* __restrict__ ov_cnt,
                                                  const float* __restrict__ b,
                                                  float* __restrict__ out, int n) {
    int wave = threadIdx.x >> 6;
    int lane = threadIdx.x & 63;
    int node = blockIdx.x * 4 + wave;
    if (node >= n) return;
    int beg = node * CAP;
    int end = beg + min(cnt[node], CAP);
    float acc = 0.f;
    for (int base = beg; base < end; base += 64) {
        int c = min(64, end - base);
        int sv = 0; float wv = 0.f;
        if (lane < c) {
            int2 iv = csr[base + lane];
            sv = iv.x; wv = __int_as_float(iv.y);
        }
        int j = 0;
        for (; j + 4 <= c; j += 4) {
            int s0 = __shfl(sv, j, 64),     s1 = __shfl(sv, j + 1, 64);
            int s2 = __shfl(sv, j + 2, 64), s3 = __shfl(sv, j + 3, 64);
            float w0 = __shfl(wv, j, 64),     w1 = __shfl(wv, j + 1, 64);
            float w2 = __shfl(wv, j + 2, 64), w3 = __shfl(wv, j + 3, 64);
            float v0 = 0.f, v1 = 0.f, v2 = 0.f, v3 = 0.f;
            if (lane < OUT_CH) {
                v0 = bf2f(h[(size_t)s0 * OUT_CH + lane]);
                v1 = bf2f(h[(size_t)s1 * OUT_CH + lane]);
                v2 = bf2f(h[(size_t)s2 * OUT_CH + lane]);
                v3 = bf2f(h[(size_t)s3 * OUT_CH + lane]);
            }
            acc += v0 * w0 + v1 * w1 + v2 * w2 + v3 * w3;
        }
        for (; j < c; ++j) {
            int s0 = __shfl(sv, j, 64);
            float w0 = __shfl(wv, j, 64);
            if (lane < OUT_CH) acc += bf2f(h[(size_t)s0 * OUT_CH + lane]) * w0;
        }
    }
    int L = min(*ov_cnt, OV_CAP);
    for (int i = 0; i < L; ++i) {
        int4 e = ov[i];
        if (e.z == node && lane < OUT_CH)
            acc += bf2f(h[(size_t)e.x * OUT_CH + lane]) * __int_as_float(e.y);
    }
    float val = 0.f, v = -INFINITY;
    if (lane < OUT_CH) {
        val = acc + b[lane];
        v = val;
    }
#pragma unroll
    for (int off = 32; off; off >>= 1)
        v = fmaxf(v, __shfl_xor(v, off, 64));
    float ex = (lane < OUT_CH) ? expf(val - v) : 0.f;
#pragma unroll
    for (int off = 32; off; off >>= 1)
        ex += __shfl_xor(ex, off, 64);
    float ls = logf(ex);
    if (lane < OUT_CH) out[(size_t)node * OUT_CH + lane] = val - v - ls;
}

// ---------------------------------------------------------------------------
extern "C" void kernel_launch(void* const* d_in, const int* in_sizes, int n_in,
                              void* d_out, int out_size, void* d_ws, size_t ws_size,
                              hipStream_t stream) {
    const float* x   = (const float*)d_in[0];
    const int*  eidx = (const int*)d_in[1];
    const float* ew  = (const float*)d_in[2];
    const float* W1  = (const float*)d_in[3];
    const float* b1  = (const float*)d_in[4];
    const float* W2  = (const float*)d_in[5];
    const float* b2  = (const float*)d_in[6];
    const float* W3  = (const float*)d_in[7];
    const float* b3  = (const float*)d_in[8];
    const int* src = eidx;
    const int* dst = eidx + N_EDGES;
    float* out = (float*)d_out;

    short* region0 = (short*)d_ws;                          // xq(fp8) / h2p(fp8)
    short* region1 = region0 + (size_t)N_NODES * HID;       // aggX / h3p
    short* H1   = region1 + (size_t)N_NODES * IN_CH;
    short* H2   = H1 + (size_t)N_NODES * HID;
    short* Wt1  = H2 + (size_t)N_NODES * HID;
    short* Wt2  = Wt1 + HID * IN_CH;
    short* Wt3  = Wt2 + HID * HID;
    int*   cnt     = (int*)(Wt3 + OUT_CH * HID);            // N_NODES + ov_cnt
    int*   ov_cnt  = cnt + N_NODES;
    int2*  csr     = (int2*)(cnt + N_NODES + 2);            // N_NODES*CAP int2
    int4*  ovbuf   = (int4*)(csr + (size_t)N_NODES * CAP);  // OV_CAP int4

    unsigned char* xq  = (unsigned char*)region0;           // fp8 chunk-major, 6.4 MB
    unsigned char* h2p = (unsigned char*)region0;           // fp8 chunk-major, 12.8 MB
    short* aggX = region1;
    short* h3p  = region1;

    dim3 blk(256);

    // ---- fused prologue: CSR fill + x cast + weight casts (independent parts)
    hipMemsetAsync(cnt, 0, (N_NODES + 1) * sizeof(int), stream);
    prologue<<<FILL_BLOCKS + CASTX_BLOCKS + WT_BLOCKS, blk, 0, stream>>>(
        src, dst, ew, cnt, csr, ovbuf, ov_cnt,
        (const float4*)x, xq, W1, W2, W3, Wt1, Wt2, Wt3);

    // ---- layer 1 (swapped): aggX = gather(xq); H1 = relu(aggX@W1 + b1)
    {
        dim3 grid((N_NODES + 15) / 16, 2);   // y = feature chunk (2 x 64)
        gather_x_fp8<<<grid, blk, 0, stream>>>(
            xq, cnt, csr, ovbuf, ov_cnt, (unsigned short*)aggX);
    }
    {
        dim3 grid((HID + 63) / 64, (N_NODES + 127) / 128);
        mfma_gemm<1><<<grid, blk, 0, stream>>>(aggX, Wt1, H1, N_NODES, IN_CH, HID, b1, 1);
    }

    // ---- layer 2: h2p = fp8(H1@W2) chunk-major ; H2 = relu(gather(h2p) + b2)
    {
        dim3 grid((HID + 63) / 64, (N_NODES + 127) / 128);
        mfma_gemm<3><<<grid, blk, 0, stream>>>(H1, Wt2, h2p, N_NODES, HID, HID, nullptr, 0);
    }
    {
        dim3 grid((N_NODES + 31) / 32, 4);   // y = feature chunk (4 x 64), 32 nodes/blk
        gather_h_fp8<<<grid, blk, 0, stream>>>(
            h2p, cnt, csr, ovbuf, ov_cnt, b2, (unsigned short*)H2);
    }

    // ---- layer 3: h3p = H2@W3 (bf16) ; out = log_softmax(gather(h3p) + b3)
    {
        dim3 grid((OUT_CH + 63) / 64, (N_NODES + 127) / 128);
        mfma_gemm<1><<<grid, blk, 0, stream>>>(H2, Wt3, h3p, N_NODES, HID, OUT_CH, nullptr, 0);
    }
    gather_lsm<<<(N_NODES + 3) / 4, blk, 0, stream>>>(
        (const unsigned short*)h3p, cnt, csr, ovbuf, ov_cnt, b3, out, N_NODES);
}